// Round 1
// baseline (1224.862 us; speedup 1.0000x reference)
//
#include <hip/hip_runtime.h>
#include <math.h>

#define N_SUBN   20000
#define E_EDGES  400000
#define R_REL    16
#define H_DIM    256
#define NBINS    (N_SUBN * R_REL)          // 320000 (dst,rel) buckets
#define SCAN_CHUNK 2048
#define NSCAN_BLOCKS ((NBINS + SCAN_CHUNK - 1) / SCAN_CHUNK)   // 157
#define NPAIRS   4096
#define TILE_N   32
#define D2       512

// ---------------- gather: h0 = emb[node_ids] ----------------
__global__ void k_gather(const float* __restrict__ emb, const int* __restrict__ nid,
                         float* __restrict__ h0) {
    int t = blockIdx.x * blockDim.x + threadIdx.x;   // 20000*64 float4 slots
    int node = t >> 6, c = (t & 63) << 2;
    if (node >= N_SUBN) return;
    const float4 s = *reinterpret_cast<const float4*>(emb + (size_t)nid[node] * H_DIM + c);
    *reinterpret_cast<float4*>(h0 + (size_t)node * H_DIM + c) = s;
}

// ---------------- CSR build over seg = dst*R + etype ----------------
__global__ void k_count(const int* __restrict__ dst, const int* __restrict__ ety,
                        int* __restrict__ cnt) {
    int e = blockIdx.x * 256 + threadIdx.x;
    if (e < E_EDGES) atomicAdd(&cnt[dst[e] * R_REL + ety[e]], 1);
}

__global__ void k_scan1(int* __restrict__ data, int* __restrict__ bs) {
    __shared__ int ts[256];
    int base = blockIdx.x * SCAN_CHUNK + threadIdx.x * 8;
    int v[8]; int s = 0;
#pragma unroll
    for (int j = 0; j < 8; j++) {
        int idx = base + j;
        v[j] = (idx < NBINS) ? data[idx] : 0;
        s += v[j];
    }
    ts[threadIdx.x] = s;
    __syncthreads();
    for (int off = 1; off < 256; off <<= 1) {
        int add = (threadIdx.x >= (unsigned)off) ? ts[threadIdx.x - off] : 0;
        __syncthreads();
        ts[threadIdx.x] += add;
        __syncthreads();
    }
    int excl = ts[threadIdx.x] - s;
    if (threadIdx.x == 255) bs[blockIdx.x] = ts[255];
    int run = excl;
#pragma unroll
    for (int j = 0; j < 8; j++) {
        int idx = base + j;
        if (idx < NBINS) data[idx] = run;
        run += v[j];
    }
}

__global__ void k_scan2(int* __restrict__ bs) {
    __shared__ int ls[NSCAN_BLOCKS];
    if (threadIdx.x < NSCAN_BLOCKS) ls[threadIdx.x] = bs[threadIdx.x];
    __syncthreads();
    if (threadIdx.x == 0) {
        int run = 0;
        for (int i = 0; i < NSCAN_BLOCKS; i++) { int t = ls[i]; ls[i] = run; run += t; }
    }
    __syncthreads();
    if (threadIdx.x < NSCAN_BLOCKS) bs[threadIdx.x] = ls[threadIdx.x];
}

__global__ void k_scan3(int* __restrict__ data, const int* __restrict__ bs,
                        int* __restrict__ cursor) {
    int idx = blockIdx.x * 256 + threadIdx.x;
    if (idx < NBINS) {
        int v = data[idx] + bs[idx / SCAN_CHUNK];
        data[idx] = v;
        cursor[idx] = v;
    }
    if (idx == 0) data[NBINS] = E_EDGES;
}

__global__ void k_scatter(const int* __restrict__ src, const int* __restrict__ dst,
                          const int* __restrict__ ety, const float* __restrict__ nrm,
                          int* __restrict__ cursor, int2* __restrict__ es) {
    int e = blockIdx.x * 256 + threadIdx.x;
    if (e >= E_EDGES) return;
    int seg = dst[e] * R_REL + ety[e];
    int pos = atomicAdd(&cursor[seg], 1);
    es[pos] = make_int2(src[e], __float_as_int(nrm[e]));
}

// ---------------- fused RGCN-BDD layer ----------------
// block = 32 dst nodes, 256 threads (thread = output feature o).
// For each relation r: waves build aggL[t][:] = sum_{edges(n0+t,r)} x[src]*norm,
// then all threads FMA aggL against streamed W[r] column; finally self-loop GEMM + bias.
__global__ __launch_bounds__(256) void k_layer(
    const float* __restrict__ hin, const int2* __restrict__ es, const int* __restrict__ segoff,
    const float* __restrict__ W, const float* __restrict__ loopw, const float* __restrict__ bias,
    float* __restrict__ hout) {
    __shared__ float aggL[TILE_N][H_DIM];
    const int n0 = blockIdx.x * TILE_N;
    const int tid = threadIdx.x;
    const int lane = tid & 63, wvid = tid >> 6;
    const int o = tid, b = o >> 5, o32 = o & 31;

    float acc[TILE_N];
#pragma unroll
    for (int t = 0; t < TILE_N; t++) acc[t] = 0.f;

    for (int r = 0; r < R_REL; r++) {
        // edge aggregation: wave wvid owns rows t = wvid, wvid+4, ...
        for (int j = 0; j < 8; j++) {
            int t = wvid + 4 * j;
            int bin = (n0 + t) * R_REL + r;
            int beg = segoff[bin], end = segoff[bin + 1];
            float4 f = make_float4(0.f, 0.f, 0.f, 0.f);
            for (int e = beg; e < end; e++) {
                int2 ed = es[e];
                float nm = __int_as_float(ed.y);
                const float4 xv = *reinterpret_cast<const float4*>(
                    hin + (size_t)ed.x * H_DIM + (lane << 2));
                f.x += xv.x * nm; f.y += xv.y * nm; f.z += xv.z * nm; f.w += xv.w * nm;
            }
            *reinterpret_cast<float4*>(&aggL[t][lane << 2]) = f;
        }
        __syncthreads();
        // transform: acc[t] += sum_i aggL[t][b*32+i] * W[r][b][i][o32]
        float wcol[32];
        const float* Wr = W + (size_t)(r * 8 + b) * 1024 + o32;
#pragma unroll
        for (int i = 0; i < 32; i++) wcol[i] = Wr[i * 32];
#pragma unroll
        for (int t = 0; t < TILE_N; t++) {
            const float4* ar = reinterpret_cast<const float4*>(&aggL[t][b << 5]);
#pragma unroll
            for (int i4 = 0; i4 < 8; i4++) {
                float4 a = ar[i4];
                acc[t] += a.x * wcol[i4 * 4 + 0] + a.y * wcol[i4 * 4 + 1]
                        + a.z * wcol[i4 * 4 + 2] + a.w * wcol[i4 * 4 + 3];
            }
        }
        __syncthreads();
    }

    // self-loop: stage h tile, then acc[t] += sum_k h[t][k] * loopw[k][o]
    for (int j = 0; j < 8; j++) {
        int t = wvid + 4 * j;
        *reinterpret_cast<float4*>(&aggL[t][lane << 2]) =
            *reinterpret_cast<const float4*>(hin + (size_t)(n0 + t) * H_DIM + (lane << 2));
    }
    __syncthreads();
    for (int kc = 0; kc < 8; kc++) {
        float wcol[32];
        const float* Lr = loopw + (size_t)(kc * 32) * H_DIM + o;
#pragma unroll
        for (int i = 0; i < 32; i++) wcol[i] = Lr[i * H_DIM];
#pragma unroll
        for (int t = 0; t < TILE_N; t++) {
            const float4* ar = reinterpret_cast<const float4*>(&aggL[t][kc << 5]);
#pragma unroll
            for (int i4 = 0; i4 < 8; i4++) {
                float4 a = ar[i4];
                acc[t] += a.x * wcol[i4 * 4 + 0] + a.y * wcol[i4 * 4 + 1]
                        + a.z * wcol[i4 * 4 + 2] + a.w * wcol[i4 * 4 + 3];
            }
        }
    }
    float bo = bias[o];
#pragma unroll
    for (int t = 0; t < TILE_N; t++)
        hout[(size_t)(n0 + t) * H_DIM + o] = acc[t] + bo;
}

// ---------------- fused concat + fc1 + relu + fc2 + sigmoid ----------------
// block = 16 pairs, 512 threads (thread = fc1 output feature o).
__global__ __launch_bounds__(512) void k_mlp(
    const float* __restrict__ h, const int* __restrict__ drugs, const int* __restrict__ targets,
    const float* __restrict__ W1, const float* __restrict__ b1f,
    const float* __restrict__ W2, const float* __restrict__ b2f,
    float* __restrict__ outp) {
    __shared__ float xp[16][D2];
    __shared__ float red[16][8];
    const int tid = threadIdx.x;
    const int p0 = blockIdx.x * 16;
    for (int p = 0; p < 16; p++) {
        int di = drugs[p0 + p], ti = targets[p0 + p];
        float v = (tid < H_DIM) ? h[(size_t)di * H_DIM + tid]
                                : h[(size_t)ti * H_DIM + (tid - H_DIM)];
        xp[p][tid] = v;
    }
    __syncthreads();
    float acc[16];
#pragma unroll
    for (int p = 0; p < 16; p++) acc[p] = 0.f;
    for (int kc = 0; kc < 16; kc++) {
        float wv[32];
        const float* Wc = W1 + (size_t)(kc * 32) * D2 + tid;
#pragma unroll
        for (int i = 0; i < 32; i++) wv[i] = Wc[i * D2];
#pragma unroll
        for (int p = 0; p < 16; p++) {
            const float4* xr = reinterpret_cast<const float4*>(&xp[p][kc << 5]);
#pragma unroll
            for (int i4 = 0; i4 < 8; i4++) {
                float4 a = xr[i4];
                acc[p] += a.x * wv[i4 * 4 + 0] + a.y * wv[i4 * 4 + 1]
                        + a.z * wv[i4 * 4 + 2] + a.w * wv[i4 * 4 + 3];
            }
        }
    }
    float b1o = b1f[tid], w2o = W2[tid];
    int lane = tid & 63, wid = tid >> 6;
#pragma unroll
    for (int p = 0; p < 16; p++) {
        float rv = acc[p] + b1o;
        rv = rv > 0.f ? rv : 0.f;
        float c = rv * w2o;
        for (int off = 32; off > 0; off >>= 1) c += __shfl_down(c, off, 64);
        if (lane == 0) red[p][wid] = c;
    }
    __syncthreads();
    if (tid < 16) {
        float s = 0.f;
#pragma unroll
        for (int w = 0; w < 8; w++) s += red[tid][w];
        s += b2f[0];
        outp[p0 + tid] = 1.f / (1.f + __expf(-s));
    }
}

extern "C" void kernel_launch(void* const* d_in, const int* in_sizes, int n_in,
                              void* d_out, int out_size, void* d_ws, size_t ws_size,
                              hipStream_t stream) {
    (void)in_sizes; (void)n_in; (void)out_size; (void)ws_size;
    const int*   drugs   = (const int*)d_in[0];
    const int*   targets = (const int*)d_in[1];
    const int*   nid     = (const int*)d_in[2];
    const int*   src     = (const int*)d_in[3];
    const int*   dst     = (const int*)d_in[4];
    const int*   ety     = (const int*)d_in[5];
    const float* nrm     = (const float*)d_in[6];
    const float* emb     = (const float*)d_in[7];
    const float* w1      = (const float*)d_in[8];
    const float* lw1     = (const float*)d_in[9];
    const float* b1      = (const float*)d_in[10];
    const float* w2      = (const float*)d_in[11];
    const float* lw2     = (const float*)d_in[12];
    const float* b2      = (const float*)d_in[13];
    const float* fc1W    = (const float*)d_in[14];
    const float* fc1b    = (const float*)d_in[15];
    const float* fc2W    = (const float*)d_in[16];
    const float* fc2b    = (const float*)d_in[17];
    float* outp = (float*)d_out;

    char* ws = (char*)d_ws;
    float* hA     = (float*)(ws);                   // 20,480,000 B  (h0, later h2)
    float* hB     = (float*)(ws + 20480000);        // 20,480,000 B  (h1)
    int*   segoff = (int*)  (ws + 40960000);        // (NBINS+1)*4 = 1,280,004 B
    int*   cursor = (int*)  (ws + 42240512);        // 1,280,000 B
    int*   bs     = (int*)  (ws + 43521024);        // 628 B
    int2*  es     = (int2*) (ws + 43522048);        // 3,200,000 B   total ≈ 46.7 MB

    hipMemsetAsync(segoff, 0, NBINS * sizeof(int), stream);
    k_gather <<<5000, 256, 0, stream>>>(emb, nid, hA);
    k_count  <<<(E_EDGES + 255) / 256, 256, 0, stream>>>(dst, ety, segoff);
    k_scan1  <<<NSCAN_BLOCKS, 256, 0, stream>>>(segoff, bs);
    k_scan2  <<<1, 256, 0, stream>>>(bs);
    k_scan3  <<<(NBINS + 255) / 256, 256, 0, stream>>>(segoff, bs, cursor);
    k_scatter<<<(E_EDGES + 255) / 256, 256, 0, stream>>>(src, dst, ety, nrm, cursor, es);
    k_layer  <<<N_SUBN / TILE_N, 256, 0, stream>>>(hA, es, segoff, w1, lw1, b1, hB);
    k_layer  <<<N_SUBN / TILE_N, 256, 0, stream>>>(hB, es, segoff, w2, lw2, b2, hA);
    k_mlp    <<<NPAIRS / 16, 512, 0, stream>>>(hA, drugs, targets, fc1W, fc1b, fc2W, fc2b, outp);
}

// Round 3
// 681.486 us; speedup vs baseline: 1.7973x; 1.7973x over previous
//
#include <hip/hip_runtime.h>
#include <math.h>

typedef __attribute__((ext_vector_type(8))) short short8;
typedef __attribute__((ext_vector_type(4))) float f32x4;

#define N_SUBN   20000
#define E_EDGES  400000
#define R_REL    16
#define H_DIM    256
#define NBINS    (N_SUBN * R_REL)          // 320000 (dst,rel) buckets
#define SCAN_CHUNK 2048
#define NSCAN_BLOCKS ((NBINS + SCAN_CHUNK - 1) / SCAN_CHUNK)   // 157
#define NPAIRS   4096
#define TILE_N   64
#define NT_BLOCKS ((N_SUBN + TILE_N - 1) / TILE_N)             // 313
#define D2       512

// ---- bf16 hi/lo split helpers (RNE) ----
__device__ __forceinline__ ushort f2bf(float x) {
    uint u = __float_as_uint(x);
    u += 0x7fffu + ((u >> 16) & 1u);
    return (ushort)(u >> 16);
}
__device__ __forceinline__ float bf2f(ushort h) {
    return __uint_as_float(((uint)h) << 16);
}

// ---------------- gather: h0 = emb[node_ids] ----------------
__global__ void k_gather(const float* __restrict__ emb, const int* __restrict__ nid,
                         float* __restrict__ h0) {
    int t = blockIdx.x * blockDim.x + threadIdx.x;   // 20000*64 float4 slots
    int node = t >> 6, c = (t & 63) << 2;
    if (node >= N_SUBN) return;
    const float4 s = *reinterpret_cast<const float4*>(emb + (size_t)nid[node] * H_DIM + c);
    *reinterpret_cast<float4*>(h0 + (size_t)node * H_DIM + c) = s;
}

// ---------------- CSR build over bin = dst*R + etype ----------------
__global__ void k_count(const int* __restrict__ dst, const int* __restrict__ ety,
                        int* __restrict__ cnt) {
    int e = blockIdx.x * 256 + threadIdx.x;
    if (e < E_EDGES) atomicAdd(&cnt[dst[e] * R_REL + ety[e]], 1);
}

__global__ void k_scan1(int* __restrict__ data, int* __restrict__ bs) {
    __shared__ int ts[256];
    int base = blockIdx.x * SCAN_CHUNK + threadIdx.x * 8;
    int v[8]; int s = 0;
#pragma unroll
    for (int j = 0; j < 8; j++) {
        int idx = base + j;
        v[j] = (idx < NBINS) ? data[idx] : 0;
        s += v[j];
    }
    ts[threadIdx.x] = s;
    __syncthreads();
    for (int off = 1; off < 256; off <<= 1) {
        int add = (threadIdx.x >= (unsigned)off) ? ts[threadIdx.x - off] : 0;
        __syncthreads();
        ts[threadIdx.x] += add;
        __syncthreads();
    }
    int excl = ts[threadIdx.x] - s;
    if (threadIdx.x == 255) bs[blockIdx.x] = ts[255];
    int run = excl;
#pragma unroll
    for (int j = 0; j < 8; j++) {
        int idx = base + j;
        if (idx < NBINS) data[idx] = run;
        run += v[j];
    }
}

__global__ void k_scan2(int* __restrict__ bs) {
    __shared__ int ls[NSCAN_BLOCKS];
    if (threadIdx.x < NSCAN_BLOCKS) ls[threadIdx.x] = bs[threadIdx.x];
    __syncthreads();
    if (threadIdx.x == 0) {
        int run = 0;
        for (int i = 0; i < NSCAN_BLOCKS; i++) { int t = ls[i]; ls[i] = run; run += t; }
    }
    __syncthreads();
    if (threadIdx.x < NSCAN_BLOCKS) bs[threadIdx.x] = ls[threadIdx.x];
}

__global__ void k_scan3(int* __restrict__ data, const int* __restrict__ bs) {
    int idx = blockIdx.x * 256 + threadIdx.x;
    if (idx < NBINS) data[idx] = data[idx] + bs[idx / SCAN_CHUNK];
}

// scatter increments segend in place: post-scatter segend[bin] = END of bin,
// beg(bin) = (bin==0) ? 0 : segend[bin-1]. Edge packed: (src<<17) | norm_q17.
__global__ void k_scatter(const int* __restrict__ src, const int* __restrict__ dst,
                          const int* __restrict__ ety, const float* __restrict__ nrm,
                          int* __restrict__ segend, uint* __restrict__ es) {
    int e = blockIdx.x * 256 + threadIdx.x;
    if (e >= E_EDGES) return;
    int bin = dst[e] * R_REL + ety[e];
    int pos = atomicAdd(&segend[bin], 1);
    float n = nrm[e];
    uint q = (uint)fminf(n * 131072.f + 0.5f, 131071.f);
    es[pos] = ((uint)src[e] << 17) | q;
}

// ---------------- W fragment pre-pack (bf16 hi/lo, MFMA B-layout) ----------------
// wfrag: frag f = (r*8+b)*2+ot ; per frag 2 planes (hi,lo) x 64 lanes x 8 bf16.
// B[k][n] for lane l: k = (l>>4)*8+j, n = ot*16 + (l&15); value = w[r][b][k][n_local]
__global__ void k_prep_w(const float* __restrict__ w, ushort* __restrict__ wfrag) {
    int t = blockIdx.x * 256 + threadIdx.x;   // 256 frags * 64 lanes = 16384
    int lane = t & 63, f = t >> 6;
    int ot = f & 1, rb = f >> 1;              // rb = r*8+b
    int kbase = (lane >> 4) * 8, n = ot * 16 + (lane & 15);
    ushort hv[8], lv[8];
#pragma unroll
    for (int j = 0; j < 8; j++) {
        float x = w[(size_t)(rb * 32 + kbase + j) * 32 + n];
        ushort h = f2bf(x);
        ushort l = f2bf(x - bf2f(h));
        hv[j] = h; lv[j] = l;
    }
    *reinterpret_cast<short8*>(wfrag + ((size_t)(f * 2 + 0) * 64 + lane) * 8) =
        *reinterpret_cast<short8*>(hv);
    *reinterpret_cast<short8*>(wfrag + ((size_t)(f * 2 + 1) * 64 + lane) * 8) =
        *reinterpret_cast<short8*>(lv);
}

// lwfrag: frag g = kt*16+ot (kt 0..7, ot 0..15); B[k][n]: k = kt*32+(l>>4)*8+j,
// n = ot*16+(l&15); value = loopw[k*256+n]
__global__ void k_prep_lw(const float* __restrict__ lw, ushort* __restrict__ lwfrag) {
    int t = blockIdx.x * 256 + threadIdx.x;   // 128 frags * 64 lanes = 8192
    int lane = t & 63, g = t >> 6;
    int kt = g >> 4, ot = g & 15;
    int kbase = kt * 32 + (lane >> 4) * 8, n = ot * 16 + (lane & 15);
    ushort hv[8], lv[8];
#pragma unroll
    for (int j = 0; j < 8; j++) {
        float x = lw[(size_t)(kbase + j) * H_DIM + n];
        ushort h = f2bf(x);
        ushort l = f2bf(x - bf2f(h));
        hv[j] = h; lv[j] = l;
    }
    *reinterpret_cast<short8*>(lwfrag + ((size_t)(g * 2 + 0) * 64 + lane) * 8) =
        *reinterpret_cast<short8*>(hv);
    *reinterpret_cast<short8*>(lwfrag + ((size_t)(g * 2 + 1) * 64 + lane) * 8) =
        *reinterpret_cast<short8*>(lv);
}

// ---------------- fused RGCN-BDD layer (MFMA, bf16 hi/lo 4-term) ----------------
// block = 64 dst nodes, 512 threads = 8 waves. Wave w owns output block b=w
// (cols 32w..32w+31, otiles ot=0,1) across all 4 m-tiles (16 nodes each).
// Per relation: each wave aggregates 8 nodes (CSR) into XOR-swizzled LDS hi/lo
// bf16 planes; then MFMA against prepacked W frags. f32 acc in VGPR throughout.
__global__ __launch_bounds__(512) void k_layer(
    const float* __restrict__ hin, const uint* __restrict__ es, const int* __restrict__ segend,
    const ushort* __restrict__ wfrag, const ushort* __restrict__ lwfrag,
    const float* __restrict__ bias, float* __restrict__ hout) {
    __shared__ __align__(16) ushort aggH[TILE_N * H_DIM];
    __shared__ __align__(16) ushort aggLo[TILE_N * H_DIM];
    char* cH = (char*)aggH;
    char* cL = (char*)aggLo;
    const int n0 = blockIdx.x * TILE_N;
    const int tid = threadIdx.x;
    const int lane = tid & 63, wv = tid >> 6;
    const int col = lane & 15, kg = lane >> 4;
    const short8* wf  = (const short8*)wfrag;
    const short8* lwf = (const short8*)lwfrag;

    f32x4 acc[4][2];
#pragma unroll
    for (int mt = 0; mt < 4; ++mt)
#pragma unroll
        for (int ot = 0; ot < 2; ++ot) acc[mt][ot] = (f32x4){0.f, 0.f, 0.f, 0.f};

    for (int r = 0; r < R_REL; ++r) {
        __syncthreads();   // previous iteration's LDS reads done before overwrite
        for (int i = 0; i < 8; ++i) {
            int t = 8 * wv + i;
            int node = n0 + t;
            float sx = 0.f, sy = 0.f, sz = 0.f, sw = 0.f;
            if (node < N_SUBN) {
                int bin = node * R_REL + r;
                int beg = (bin == 0) ? 0 : segend[bin - 1];
                int end = segend[bin];
                for (int e = beg; e < end; ++e) {
                    uint pk = es[e];
                    int s = (int)(pk >> 17);
                    float nm = (float)(pk & 0x1FFFFu) * (1.f / 131072.f);
                    const float4 xv = *reinterpret_cast<const float4*>(
                        hin + (size_t)s * H_DIM + (lane << 2));
                    sx = fmaf(xv.x, nm, sx); sy = fmaf(xv.y, nm, sy);
                    sz = fmaf(xv.z, nm, sz); sw = fmaf(xv.w, nm, sw);
                }
            }
            ushort h0 = f2bf(sx), h1 = f2bf(sy), h2 = f2bf(sz), h3 = f2bf(sw);
            ushort l0 = f2bf(sx - bf2f(h0)), l1 = f2bf(sy - bf2f(h1));
            ushort l2 = f2bf(sz - bf2f(h2)), l3 = f2bf(sw - bf2f(h3));
            uint2 ph = make_uint2((uint)h0 | ((uint)h1 << 16), (uint)h2 | ((uint)h3 << 16));
            uint2 pl = make_uint2((uint)l0 | ((uint)l1 << 16), (uint)l2 | ((uint)l3 << 16));
            uint byte = (uint)(t * 512) + ((((lane >> 1) ^ (t & 7)) << 4) | ((lane & 1) << 3));
            *(uint2*)(cH + byte) = ph;
            *(uint2*)(cL + byte) = pl;
        }
        __syncthreads();
#pragma unroll
        for (int ot = 0; ot < 2; ++ot) {
            int f = (r * 8 + wv) * 2 + ot;
            short8 Bh = wf[(f * 2 + 0) * 64 + lane];
            short8 Bl = wf[(f * 2 + 1) * 64 + lane];
#pragma unroll
            for (int mt = 0; mt < 4; ++mt) {
                int row = mt * 16 + col;
                uint ab = (uint)(row * 512) + ((uint)((wv * 4 + kg) ^ (row & 7)) << 4);
                short8 Ah = *(const short8*)(cH + ab);
                short8 Al = *(const short8*)(cL + ab);
                f32x4 a = acc[mt][ot];
                a = __builtin_amdgcn_mfma_f32_16x16x32_bf16(Ah, Bh, a, 0, 0, 0);
                a = __builtin_amdgcn_mfma_f32_16x16x32_bf16(Ah, Bl, a, 0, 0, 0);
                a = __builtin_amdgcn_mfma_f32_16x16x32_bf16(Al, Bh, a, 0, 0, 0);
                a = __builtin_amdgcn_mfma_f32_16x16x32_bf16(Al, Bl, a, 0, 0, 0);
                acc[mt][ot] = a;
            }
        }
    }

    // ---- self-loop: restage h tile as hi/lo, K=256 MFMA sweep ----
    __syncthreads();
    for (int i = 0; i < 8; ++i) {
        int t = 8 * wv + i;
        int node = n0 + t;
        float4 xv = make_float4(0.f, 0.f, 0.f, 0.f);
        if (node < N_SUBN)
            xv = *reinterpret_cast<const float4*>(hin + (size_t)node * H_DIM + (lane << 2));
        ushort h0 = f2bf(xv.x), h1 = f2bf(xv.y), h2 = f2bf(xv.z), h3 = f2bf(xv.w);
        ushort l0 = f2bf(xv.x - bf2f(h0)), l1 = f2bf(xv.y - bf2f(h1));
        ushort l2 = f2bf(xv.z - bf2f(h2)), l3 = f2bf(xv.w - bf2f(h3));
        uint2 ph = make_uint2((uint)h0 | ((uint)h1 << 16), (uint)h2 | ((uint)h3 << 16));
        uint2 pl = make_uint2((uint)l0 | ((uint)l1 << 16), (uint)l2 | ((uint)l3 << 16));
        uint byte = (uint)(t * 512) + ((((lane >> 1) ^ (t & 7)) << 4) | ((lane & 1) << 3));
        *(uint2*)(cH + byte) = ph;
        *(uint2*)(cL + byte) = pl;
    }
    __syncthreads();
#pragma unroll
    for (int kt = 0; kt < 8; ++kt) {
#pragma unroll
        for (int ot = 0; ot < 2; ++ot) {
            int g = kt * 16 + 2 * wv + ot;
            short8 Bh = lwf[(g * 2 + 0) * 64 + lane];
            short8 Bl = lwf[(g * 2 + 1) * 64 + lane];
#pragma unroll
            for (int mt = 0; mt < 4; ++mt) {
                int row = mt * 16 + col;
                uint ab = (uint)(row * 512) + ((uint)((kt * 4 + kg) ^ (row & 7)) << 4);
                short8 Ah = *(const short8*)(cH + ab);
                short8 Al = *(const short8*)(cL + ab);
                f32x4 a = acc[mt][ot];
                a = __builtin_amdgcn_mfma_f32_16x16x32_bf16(Ah, Bh, a, 0, 0, 0);
                a = __builtin_amdgcn_mfma_f32_16x16x32_bf16(Ah, Bl, a, 0, 0, 0);
                a = __builtin_amdgcn_mfma_f32_16x16x32_bf16(Al, Bh, a, 0, 0, 0);
                a = __builtin_amdgcn_mfma_f32_16x16x32_bf16(Al, Bl, a, 0, 0, 0);
                acc[mt][ot] = a;
            }
        }
    }

    // ---- epilogue: C/D layout col=lane&15, row=(lane>>4)*4+reg ----
#pragma unroll
    for (int mt = 0; mt < 4; ++mt) {
        int nbase = n0 + mt * 16 + kg * 4;
#pragma unroll
        for (int ot = 0; ot < 2; ++ot) {
            int o = 32 * wv + ot * 16 + col;
            float bo = bias[o];
#pragma unroll
            for (int rg = 0; rg < 4; ++rg) {
                int n = nbase + rg;
                if (n < N_SUBN)
                    hout[(size_t)n * H_DIM + o] = acc[mt][ot][rg] + bo;
            }
        }
    }
}

// ---------------- fused concat + fc1 + relu + fc2 + sigmoid ----------------
__global__ __launch_bounds__(512) void k_mlp(
    const float* __restrict__ h, const int* __restrict__ drugs, const int* __restrict__ targets,
    const float* __restrict__ W1, const float* __restrict__ b1f,
    const float* __restrict__ W2, const float* __restrict__ b2f,
    float* __restrict__ outp) {
    __shared__ float xp[16][D2];
    __shared__ float red[16][8];
    const int tid = threadIdx.x;
    const int p0 = blockIdx.x * 16;
    for (int p = 0; p < 16; p++) {
        int di = drugs[p0 + p], ti = targets[p0 + p];
        float v = (tid < H_DIM) ? h[(size_t)di * H_DIM + tid]
                                : h[(size_t)ti * H_DIM + (tid - H_DIM)];
        xp[p][tid] = v;
    }
    __syncthreads();
    float acc[16];
#pragma unroll
    for (int p = 0; p < 16; p++) acc[p] = 0.f;
    for (int kc = 0; kc < 16; kc++) {
        float wv[32];
        const float* Wc = W1 + (size_t)(kc * 32) * D2 + tid;
#pragma unroll
        for (int i = 0; i < 32; i++) wv[i] = Wc[i * D2];
#pragma unroll
        for (int p = 0; p < 16; p++) {
            const float4* xr = reinterpret_cast<const float4*>(&xp[p][kc << 5]);
#pragma unroll
            for (int i4 = 0; i4 < 8; i4++) {
                float4 a = xr[i4];
                acc[p] += a.x * wv[i4 * 4 + 0] + a.y * wv[i4 * 4 + 1]
                        + a.z * wv[i4 * 4 + 2] + a.w * wv[i4 * 4 + 3];
            }
        }
    }
    float b1o = b1f[tid], w2o = W2[tid];
    int lane = tid & 63, wid = tid >> 6;
#pragma unroll
    for (int p = 0; p < 16; p++) {
        float rv = acc[p] + b1o;
        rv = rv > 0.f ? rv : 0.f;
        float c = rv * w2o;
        for (int off = 32; off > 0; off >>= 1) c += __shfl_down(c, off, 64);
        if (lane == 0) red[p][wid] = c;
    }
    __syncthreads();
    if (tid < 16) {
        float s = 0.f;
#pragma unroll
        for (int w = 0; w < 8; w++) s += red[tid][w];
        s += b2f[0];
        outp[p0 + tid] = 1.f / (1.f + __expf(-s));
    }
}

extern "C" void kernel_launch(void* const* d_in, const int* in_sizes, int n_in,
                              void* d_out, int out_size, void* d_ws, size_t ws_size,
                              hipStream_t stream) {
    (void)in_sizes; (void)n_in; (void)out_size; (void)ws_size;
    const int*   drugs   = (const int*)d_in[0];
    const int*   targets = (const int*)d_in[1];
    const int*   nid     = (const int*)d_in[2];
    const int*   src     = (const int*)d_in[3];
    const int*   dst     = (const int*)d_in[4];
    const int*   ety     = (const int*)d_in[5];
    const float* nrm     = (const float*)d_in[6];
    const float* emb     = (const float*)d_in[7];
    const float* w1      = (const float*)d_in[8];
    const float* lw1     = (const float*)d_in[9];
    const float* b1      = (const float*)d_in[10];
    const float* w2      = (const float*)d_in[11];
    const float* lw2     = (const float*)d_in[12];
    const float* b2      = (const float*)d_in[13];
    const float* fc1W    = (const float*)d_in[14];
    const float* fc1b    = (const float*)d_in[15];
    const float* fc2W    = (const float*)d_in[16];
    const float* fc2b    = (const float*)d_in[17];
    float* outp = (float*)d_out;

    // ws layout — total 45,413,888 B, below the 46.72 MB bound proven by round 1.
    char* ws = (char*)d_ws;
    ushort* wfrag1  = (ushort*)(ws);                    //    524,288
    ushort* wfrag2  = (ushort*)(ws + 524288);           //    524,288
    ushort* lwfrag1 = (ushort*)(ws + 1048576);          //    262,144
    ushort* lwfrag2 = (ushort*)(ws + 1310720);          //    262,144
    float*  hA      = (float*) (ws + 1572864);          // 20,480,000
    float*  hB      = (float*) (ws + 22052864);         // 20,480,000
    int*    segend  = (int*)   (ws + 42532864);         //  1,280,000
    int*    bs      = (int*)   (ws + 43812864);         //      1,024
    uint*   es      = (uint*)  (ws + 43813888);         //  1,600,000 -> end 45,413,888

    hipMemsetAsync(segend, 0, NBINS * sizeof(int), stream);
    k_prep_w <<<64, 256, 0, stream>>>(w1, wfrag1);
    k_prep_w <<<64, 256, 0, stream>>>(w2, wfrag2);
    k_prep_lw<<<32, 256, 0, stream>>>(lw1, lwfrag1);
    k_prep_lw<<<32, 256, 0, stream>>>(lw2, lwfrag2);
    k_gather <<<5000, 256, 0, stream>>>(emb, nid, hA);
    k_count  <<<(E_EDGES + 255) / 256, 256, 0, stream>>>(dst, ety, segend);
    k_scan1  <<<NSCAN_BLOCKS, 256, 0, stream>>>(segend, bs);
    k_scan2  <<<1, 256, 0, stream>>>(bs);
    k_scan3  <<<(NBINS + 255) / 256, 256, 0, stream>>>(segend, bs);
    k_scatter<<<(E_EDGES + 255) / 256, 256, 0, stream>>>(src, dst, ety, nrm, segend, es);
    k_layer  <<<NT_BLOCKS, 512, 0, stream>>>(hA, es, segend, wfrag1, lwfrag1, b1, hB);
    k_layer  <<<NT_BLOCKS, 512, 0, stream>>>(hB, es, segend, wfrag2, lwfrag2, b2, hA);
    k_mlp    <<<NPAIRS / 16, 512, 0, stream>>>(hA, drugs, targets, fc1W, fc1b, fc2W, fc2b, outp);
}

// Round 4
// 510.805 us; speedup vs baseline: 2.3979x; 1.3341x over previous
//
#include <hip/hip_runtime.h>
#include <math.h>

typedef __attribute__((ext_vector_type(8))) short short8;
typedef __attribute__((ext_vector_type(4))) float f32x4;

#define N_SUBN   20000
#define E_EDGES  400000
#define R_REL    16
#define H_DIM    256
#define NBINS    (N_SUBN * R_REL)          // 320000 (dst,rel) buckets
#define SCAN_CHUNK 2048
#define NSCAN_BLOCKS ((NBINS + SCAN_CHUNK - 1) / SCAN_CHUNK)   // 157
#define NPAIRS   4096
#define TILE_N   64
#define NT_BLOCKS ((N_SUBN + TILE_N - 1) / TILE_N)             // 313
#define D2       512

// ---- bf16 hi/lo split helpers (RNE) ----
__device__ __forceinline__ ushort f2bf(float x) {
    uint u = __float_as_uint(x);
    u += 0x7fffu + ((u >> 16) & 1u);
    return (ushort)(u >> 16);
}
__device__ __forceinline__ float bf2f(ushort h) {
    return __uint_as_float(((uint)h) << 16);
}

// ---------------- gather: h0 = emb[node_ids] ----------------
__global__ void k_gather(const float* __restrict__ emb, const int* __restrict__ nid,
                         float* __restrict__ h0) {
    int t = blockIdx.x * blockDim.x + threadIdx.x;   // 20000*64 float4 slots
    int node = t >> 6, c = (t & 63) << 2;
    if (node >= N_SUBN) return;
    const float4 s = *reinterpret_cast<const float4*>(emb + (size_t)nid[node] * H_DIM + c);
    *reinterpret_cast<float4*>(h0 + (size_t)node * H_DIM + c) = s;
}

// ---------------- CSR build over bin = dst*R + etype ----------------
__global__ void k_count(const int* __restrict__ dst, const int* __restrict__ ety,
                        int* __restrict__ cnt) {
    int e = blockIdx.x * 256 + threadIdx.x;
    if (e < E_EDGES) atomicAdd(&cnt[dst[e] * R_REL + ety[e]], 1);
}

__global__ void k_scan1(int* __restrict__ data, int* __restrict__ bs) {
    __shared__ int ts[256];
    int base = blockIdx.x * SCAN_CHUNK + threadIdx.x * 8;
    int v[8]; int s = 0;
#pragma unroll
    for (int j = 0; j < 8; j++) {
        int idx = base + j;
        v[j] = (idx < NBINS) ? data[idx] : 0;
        s += v[j];
    }
    ts[threadIdx.x] = s;
    __syncthreads();
    for (int off = 1; off < 256; off <<= 1) {
        int add = (threadIdx.x >= (unsigned)off) ? ts[threadIdx.x - off] : 0;
        __syncthreads();
        ts[threadIdx.x] += add;
        __syncthreads();
    }
    int excl = ts[threadIdx.x] - s;
    if (threadIdx.x == 255) bs[blockIdx.x] = ts[255];
    int run = excl;
#pragma unroll
    for (int j = 0; j < 8; j++) {
        int idx = base + j;
        if (idx < NBINS) data[idx] = run;
        run += v[j];
    }
}

__global__ void k_scan2(int* __restrict__ bs) {
    __shared__ int ls[NSCAN_BLOCKS];
    if (threadIdx.x < NSCAN_BLOCKS) ls[threadIdx.x] = bs[threadIdx.x];
    __syncthreads();
    if (threadIdx.x == 0) {
        int run = 0;
        for (int i = 0; i < NSCAN_BLOCKS; i++) { int t = ls[i]; ls[i] = run; run += t; }
    }
    __syncthreads();
    if (threadIdx.x < NSCAN_BLOCKS) bs[threadIdx.x] = ls[threadIdx.x];
}

__global__ void k_scan3(int* __restrict__ data, const int* __restrict__ bs) {
    int idx = blockIdx.x * 256 + threadIdx.x;
    if (idx < NBINS) data[idx] = data[idx] + bs[idx / SCAN_CHUNK];
}

// scatter increments segend in place: post-scatter segend[bin] = END of bin,
// beg(bin) = (bin==0) ? 0 : segend[bin-1]. Edge packed: (src<<17) | norm_q17.
__global__ void k_scatter(const int* __restrict__ src, const int* __restrict__ dst,
                          const int* __restrict__ ety, const float* __restrict__ nrm,
                          int* __restrict__ segend, uint* __restrict__ es) {
    int e = blockIdx.x * 256 + threadIdx.x;
    if (e >= E_EDGES) return;
    int bin = dst[e] * R_REL + ety[e];
    int pos = atomicAdd(&segend[bin], 1);
    float n = nrm[e];
    uint q = (uint)fminf(n * 131072.f + 0.5f, 131071.f);
    es[pos] = ((uint)src[e] << 17) | q;
}

// ---------------- W fragment pre-pack (bf16 hi/lo, MFMA B-layout) ----------------
__global__ void k_prep_w(const float* __restrict__ w, ushort* __restrict__ wfrag) {
    int t = blockIdx.x * 256 + threadIdx.x;   // 256 frags * 64 lanes = 16384
    int lane = t & 63, f = t >> 6;
    int ot = f & 1, rb = f >> 1;              // rb = r*8+b
    int kbase = (lane >> 4) * 8, n = ot * 16 + (lane & 15);
    ushort hv[8], lv[8];
#pragma unroll
    for (int j = 0; j < 8; j++) {
        float x = w[(size_t)(rb * 32 + kbase + j) * 32 + n];
        ushort h = f2bf(x);
        ushort l = f2bf(x - bf2f(h));
        hv[j] = h; lv[j] = l;
    }
    *reinterpret_cast<short8*>(wfrag + ((size_t)(f * 2 + 0) * 64 + lane) * 8) =
        *reinterpret_cast<short8*>(hv);
    *reinterpret_cast<short8*>(wfrag + ((size_t)(f * 2 + 1) * 64 + lane) * 8) =
        *reinterpret_cast<short8*>(lv);
}

// lwfrag: frag g = kt*16+ot (kt 0..7, ot 0..15)
__global__ void k_prep_lw(const float* __restrict__ lw, ushort* __restrict__ lwfrag) {
    int t = blockIdx.x * 256 + threadIdx.x;   // 128 frags * 64 lanes = 8192
    int lane = t & 63, g = t >> 6;
    int kt = g >> 4, ot = g & 15;
    int kbase = kt * 32 + (lane >> 4) * 8, n = ot * 16 + (lane & 15);
    ushort hv[8], lv[8];
#pragma unroll
    for (int j = 0; j < 8; j++) {
        float x = lw[(size_t)(kbase + j) * H_DIM + n];
        ushort h = f2bf(x);
        ushort l = f2bf(x - bf2f(h));
        hv[j] = h; lv[j] = l;
    }
    *reinterpret_cast<short8*>(lwfrag + ((size_t)(g * 2 + 0) * 64 + lane) * 8) =
        *reinterpret_cast<short8*>(hv);
    *reinterpret_cast<short8*>(lwfrag + ((size_t)(g * 2 + 1) * 64 + lane) * 8) =
        *reinterpret_cast<short8*>(lv);
}

// fc1frag: frag g = kt*32+ot (kt 0..15, ot 0..31); k = kt*32+(l>>4)*8+j,
// n = ot*16+(l&15); value = fc1W[k*512+n]
__global__ void k_prep_fc1(const float* __restrict__ w, ushort* __restrict__ wfrag) {
    int t = blockIdx.x * 256 + threadIdx.x;   // 512 frags * 64 lanes = 32768
    int lane = t & 63, g = t >> 6;
    int kt = g >> 5, ot = g & 31;
    int kbase = kt * 32 + (lane >> 4) * 8, n = ot * 16 + (lane & 15);
    ushort hv[8], lv[8];
#pragma unroll
    for (int j = 0; j < 8; j++) {
        float x = w[(size_t)(kbase + j) * D2 + n];
        ushort h = f2bf(x);
        ushort l = f2bf(x - bf2f(h));
        hv[j] = h; lv[j] = l;
    }
    *reinterpret_cast<short8*>(wfrag + ((size_t)(g * 2 + 0) * 64 + lane) * 8) =
        *reinterpret_cast<short8*>(hv);
    *reinterpret_cast<short8*>(wfrag + ((size_t)(g * 2 + 1) * 64 + lane) * 8) =
        *reinterpret_cast<short8*>(lv);
}

// ---------------- fused RGCN-BDD layer (MFMA, bf16 hi/lo 4-term) ----------------
__global__ __launch_bounds__(512) void k_layer(
    const float* __restrict__ hin, const uint* __restrict__ es, const int* __restrict__ segend,
    const ushort* __restrict__ wfrag, const ushort* __restrict__ lwfrag,
    const float* __restrict__ bias, float* __restrict__ hout) {
    __shared__ __align__(16) ushort aggH[TILE_N * H_DIM];
    __shared__ __align__(16) ushort aggLo[TILE_N * H_DIM];
    char* cH = (char*)aggH;
    char* cL = (char*)aggLo;
    const int n0 = blockIdx.x * TILE_N;
    const int tid = threadIdx.x;
    const int lane = tid & 63, wv = tid >> 6;
    const int col = lane & 15, kg = lane >> 4;
    const short8* wf  = (const short8*)wfrag;
    const short8* lwf = (const short8*)lwfrag;

    f32x4 acc[4][2];
#pragma unroll
    for (int mt = 0; mt < 4; ++mt)
#pragma unroll
        for (int ot = 0; ot < 2; ++ot) acc[mt][ot] = (f32x4){0.f, 0.f, 0.f, 0.f};

    for (int r = 0; r < R_REL; ++r) {
        __syncthreads();   // previous iteration's LDS reads done before overwrite
        for (int i = 0; i < 8; ++i) {
            int t = 8 * wv + i;
            int node = n0 + t;
            float sx = 0.f, sy = 0.f, sz = 0.f, sw = 0.f;
            if (node < N_SUBN) {
                int bin = node * R_REL + r;
                int beg = (bin == 0) ? 0 : segend[bin - 1];
                int end = segend[bin];
                for (int e = beg; e < end; ++e) {
                    uint pk = es[e];
                    int s = (int)(pk >> 17);
                    float nm = (float)(pk & 0x1FFFFu) * (1.f / 131072.f);
                    const float4 xv = *reinterpret_cast<const float4*>(
                        hin + (size_t)s * H_DIM + (lane << 2));
                    sx = fmaf(xv.x, nm, sx); sy = fmaf(xv.y, nm, sy);
                    sz = fmaf(xv.z, nm, sz); sw = fmaf(xv.w, nm, sw);
                }
            }
            ushort h0 = f2bf(sx), h1 = f2bf(sy), h2 = f2bf(sz), h3 = f2bf(sw);
            ushort l0 = f2bf(sx - bf2f(h0)), l1 = f2bf(sy - bf2f(h1));
            ushort l2 = f2bf(sz - bf2f(h2)), l3 = f2bf(sw - bf2f(h3));
            uint2 ph = make_uint2((uint)h0 | ((uint)h1 << 16), (uint)h2 | ((uint)h3 << 16));
            uint2 pl = make_uint2((uint)l0 | ((uint)l1 << 16), (uint)l2 | ((uint)l3 << 16));
            uint byte = (uint)(t * 512) + ((((lane >> 1) ^ (t & 7)) << 4) | ((lane & 1) << 3));
            *(uint2*)(cH + byte) = ph;
            *(uint2*)(cL + byte) = pl;
        }
        __syncthreads();
#pragma unroll
        for (int ot = 0; ot < 2; ++ot) {
            int f = (r * 8 + wv) * 2 + ot;
            short8 Bh = wf[(f * 2 + 0) * 64 + lane];
            short8 Bl = wf[(f * 2 + 1) * 64 + lane];
#pragma unroll
            for (int mt = 0; mt < 4; ++mt) {
                int row = mt * 16 + col;
                uint ab = (uint)(row * 512) + ((uint)((wv * 4 + kg) ^ (row & 7)) << 4);
                short8 Ah = *(const short8*)(cH + ab);
                short8 Al = *(const short8*)(cL + ab);
                f32x4 a = acc[mt][ot];
                a = __builtin_amdgcn_mfma_f32_16x16x32_bf16(Ah, Bh, a, 0, 0, 0);
                a = __builtin_amdgcn_mfma_f32_16x16x32_bf16(Ah, Bl, a, 0, 0, 0);
                a = __builtin_amdgcn_mfma_f32_16x16x32_bf16(Al, Bh, a, 0, 0, 0);
                a = __builtin_amdgcn_mfma_f32_16x16x32_bf16(Al, Bl, a, 0, 0, 0);
                acc[mt][ot] = a;
            }
        }
    }

    // ---- self-loop: restage h tile as hi/lo, K=256 MFMA sweep ----
    __syncthreads();
    for (int i = 0; i < 8; ++i) {
        int t = 8 * wv + i;
        int node = n0 + t;
        float4 xv = make_float4(0.f, 0.f, 0.f, 0.f);
        if (node < N_SUBN)
            xv = *reinterpret_cast<const float4*>(hin + (size_t)node * H_DIM + (lane << 2));
        ushort h0 = f2bf(xv.x), h1 = f2bf(xv.y), h2 = f2bf(xv.z), h3 = f2bf(xv.w);
        ushort l0 = f2bf(xv.x - bf2f(h0)), l1 = f2bf(xv.y - bf2f(h1));
        ushort l2 = f2bf(xv.z - bf2f(h2)), l3 = f2bf(xv.w - bf2f(h3));
        uint2 ph = make_uint2((uint)h0 | ((uint)h1 << 16), (uint)h2 | ((uint)h3 << 16));
        uint2 pl = make_uint2((uint)l0 | ((uint)l1 << 16), (uint)l2 | ((uint)l3 << 16));
        uint byte = (uint)(t * 512) + ((((lane >> 1) ^ (t & 7)) << 4) | ((lane & 1) << 3));
        *(uint2*)(cH + byte) = ph;
        *(uint2*)(cL + byte) = pl;
    }
    __syncthreads();
#pragma unroll
    for (int kt = 0; kt < 8; ++kt) {
#pragma unroll
        for (int ot = 0; ot < 2; ++ot) {
            int g = kt * 16 + 2 * wv + ot;
            short8 Bh = lwf[(g * 2 + 0) * 64 + lane];
            short8 Bl = lwf[(g * 2 + 1) * 64 + lane];
#pragma unroll
            for (int mt = 0; mt < 4; ++mt) {
                int row = mt * 16 + col;
                uint ab = (uint)(row * 512) + ((uint)((kt * 4 + kg) ^ (row & 7)) << 4);
                short8 Ah = *(const short8*)(cH + ab);
                short8 Al = *(const short8*)(cL + ab);
                f32x4 a = acc[mt][ot];
                a = __builtin_amdgcn_mfma_f32_16x16x32_bf16(Ah, Bh, a, 0, 0, 0);
                a = __builtin_amdgcn_mfma_f32_16x16x32_bf16(Ah, Bl, a, 0, 0, 0);
                a = __builtin_amdgcn_mfma_f32_16x16x32_bf16(Al, Bh, a, 0, 0, 0);
                a = __builtin_amdgcn_mfma_f32_16x16x32_bf16(Al, Bl, a, 0, 0, 0);
                acc[mt][ot] = a;
            }
        }
    }

    // ---- epilogue: C/D layout col=lane&15, row=(lane>>4)*4+reg ----
#pragma unroll
    for (int mt = 0; mt < 4; ++mt) {
        int nbase = n0 + mt * 16 + kg * 4;
#pragma unroll
        for (int ot = 0; ot < 2; ++ot) {
            int o = 32 * wv + ot * 16 + col;
            float bo = bias[o];
#pragma unroll
            for (int rg = 0; rg < 4; ++rg) {
                int n = nbase + rg;
                if (n < N_SUBN)
                    hout[(size_t)n * H_DIM + o] = acc[mt][ot][rg] + bo;
            }
        }
    }
}

// ---------------- fused concat + fc1(MFMA) + relu + fc2 + sigmoid ----------------
// block = 16 pairs, 512 threads = 8 waves. Wave wv owns fc1 output cols
// 64wv..64wv+63 (4 otiles). X tile [16][512] staged in LDS as swizzled bf16
// hi/lo planes. 16 k-steps of 32; 4-term hi/lo MFMA; f32 epilogue.
__global__ __launch_bounds__(512) void k_mlp(
    const float* __restrict__ h, const int* __restrict__ drugs, const int* __restrict__ targets,
    const ushort* __restrict__ fc1frag, const float* __restrict__ b1f,
    const float* __restrict__ W2, const float* __restrict__ b2f,
    float* __restrict__ outp) {
    __shared__ __align__(16) ushort xH[16 * D2];
    __shared__ __align__(16) ushort xL[16 * D2];
    __shared__ float red[16][8];
    char* cH = (char*)xH;
    char* cL = (char*)xL;
    const int tid = threadIdx.x;
    const int lane = tid & 63, wv = tid >> 6;
    const int col = lane & 15, kg = lane >> 4;
    const int p0 = blockIdx.x * 16;
    const short8* wf = (const short8*)fc1frag;

    // ---- stage X = [h[drug] | h[target]] as bf16 hi/lo, swizzled ----
    {
        int p = tid >> 5;                 // pair row 0..15
        int cc = (tid & 31) * 16;         // 16 consecutive k per thread
        int di = drugs[p0 + p], ti = targets[p0 + p];
        const float* srcp = (cc < H_DIM) ? (h + (size_t)di * H_DIM + cc)
                                         : (h + (size_t)ti * H_DIM + (cc - H_DIM));
#pragma unroll
        for (int j = 0; j < 2; ++j) {
            float4 a = *reinterpret_cast<const float4*>(srcp + j * 8);
            float4 b = *reinterpret_cast<const float4*>(srcp + j * 8 + 4);
            float f[8] = {a.x, a.y, a.z, a.w, b.x, b.y, b.z, b.w};
            short8 hv, lv;
#pragma unroll
            for (int q = 0; q < 8; ++q) {
                ushort hh = f2bf(f[q]);
                hv[q] = (short)hh;
                lv[q] = (short)f2bf(f[q] - bf2f(hh));
            }
            uint chunk = (uint)((tid & 31) * 2 + j);
            uint byte = (uint)p * 1024 + ((chunk ^ (uint)(p & 7)) << 4);
            *(short8*)(cH + byte) = hv;
            *(short8*)(cL + byte) = lv;
        }
    }
    __syncthreads();

    // ---- fc1 GEMM: acc[oi] over 16 k-steps ----
    f32x4 acc[4];
#pragma unroll
    for (int oi = 0; oi < 4; ++oi) acc[oi] = (f32x4){0.f, 0.f, 0.f, 0.f};

    for (int kt = 0; kt < 16; ++kt) {
        uint ab = (uint)col * 1024 + ((uint)((kt * 4 + kg) ^ (col & 7)) << 4);
        short8 Ah = *(const short8*)(cH + ab);
        short8 Al = *(const short8*)(cL + ab);
#pragma unroll
        for (int oi = 0; oi < 4; ++oi) {
            int g = kt * 32 + wv * 4 + oi;
            short8 Bh = wf[(g * 2 + 0) * 64 + lane];
            short8 Bl = wf[(g * 2 + 1) * 64 + lane];
            f32x4 a = acc[oi];
            a = __builtin_amdgcn_mfma_f32_16x16x32_bf16(Ah, Bh, a, 0, 0, 0);
            a = __builtin_amdgcn_mfma_f32_16x16x32_bf16(Ah, Bl, a, 0, 0, 0);
            a = __builtin_amdgcn_mfma_f32_16x16x32_bf16(Al, Bh, a, 0, 0, 0);
            a = __builtin_amdgcn_mfma_f32_16x16x32_bf16(Al, Bl, a, 0, 0, 0);
            acc[oi] = a;
        }
    }

    // ---- epilogue: bias + relu + dot W2, reduce over 16 col-lanes ----
    float val[4] = {0.f, 0.f, 0.f, 0.f};   // per rg (pair row kg*4+rg)
#pragma unroll
    for (int oi = 0; oi < 4; ++oi) {
        int o = 64 * wv + oi * 16 + col;
        float b1o = b1f[o], w2o = W2[o];
#pragma unroll
        for (int rg = 0; rg < 4; ++rg) {
            float y = acc[oi][rg] + b1o;
            y = y > 0.f ? y : 0.f;
            val[rg] = fmaf(y, w2o, val[rg]);
        }
    }
#pragma unroll
    for (int rg = 0; rg < 4; ++rg) {
        float v = val[rg];
        v += __shfl_xor(v, 1, 64);
        v += __shfl_xor(v, 2, 64);
        v += __shfl_xor(v, 4, 64);
        v += __shfl_xor(v, 8, 64);
        val[rg] = v;
    }
    if (col == 0) {
#pragma unroll
        for (int rg = 0; rg < 4; ++rg) red[kg * 4 + rg][wv] = val[rg];
    }
    __syncthreads();
    if (tid < 16) {
        float s = 0.f;
#pragma unroll
        for (int w = 0; w < 8; w++) s += red[tid][w];
        s += b2f[0];
        outp[p0 + tid] = 1.f / (1.f + __expf(-s));
    }
}

extern "C" void kernel_launch(void* const* d_in, const int* in_sizes, int n_in,
                              void* d_out, int out_size, void* d_ws, size_t ws_size,
                              hipStream_t stream) {
    (void)in_sizes; (void)n_in; (void)out_size; (void)ws_size;
    const int*   drugs   = (const int*)d_in[0];
    const int*   targets = (const int*)d_in[1];
    const int*   nid     = (const int*)d_in[2];
    const int*   src     = (const int*)d_in[3];
    const int*   dst     = (const int*)d_in[4];
    const int*   ety     = (const int*)d_in[5];
    const float* nrm     = (const float*)d_in[6];
    const float* emb     = (const float*)d_in[7];
    const float* w1      = (const float*)d_in[8];
    const float* lw1     = (const float*)d_in[9];
    const float* b1      = (const float*)d_in[10];
    const float* w2      = (const float*)d_in[11];
    const float* lw2     = (const float*)d_in[12];
    const float* b2      = (const float*)d_in[13];
    const float* fc1W    = (const float*)d_in[14];
    const float* fc1b    = (const float*)d_in[15];
    const float* fc2W    = (const float*)d_in[16];
    const float* fc2b    = (const float*)d_in[17];
    float* outp = (float*)d_out;

    // ws layout — total 46,462,464 B, below the 46.72 MB bound proven by round 1.
    char* ws = (char*)d_ws;
    ushort* wfrag1  = (ushort*)(ws);                    //    524,288
    ushort* wfrag2  = (ushort*)(ws + 524288);           //    524,288
    ushort* lwfrag1 = (ushort*)(ws + 1048576);          //    262,144
    ushort* lwfrag2 = (ushort*)(ws + 1310720);          //    262,144
    ushort* fc1frag = (ushort*)(ws + 1572864);          //  1,048,576
    float*  hA      = (float*) (ws + 2621440);          // 20,480,000
    float*  hB      = (float*) (ws + 23101440);         // 20,480,000
    int*    segend  = (int*)   (ws + 43581440);         //  1,280,000
    int*    bs      = (int*)   (ws + 44861440);         //      1,024
    uint*   es      = (uint*)  (ws + 44862464);         //  1,600,000 -> end 46,462,464

    hipMemsetAsync(segend, 0, NBINS * sizeof(int), stream);
    k_prep_w  <<<64, 256, 0, stream>>>(w1, wfrag1);
    k_prep_w  <<<64, 256, 0, stream>>>(w2, wfrag2);
    k_prep_lw <<<32, 256, 0, stream>>>(lw1, lwfrag1);
    k_prep_lw <<<32, 256, 0, stream>>>(lw2, lwfrag2);
    k_prep_fc1<<<128, 256, 0, stream>>>(fc1W, fc1frag);
    k_gather <<<5000, 256, 0, stream>>>(emb, nid, hA);
    k_count  <<<(E_EDGES + 255) / 256, 256, 0, stream>>>(dst, ety, segend);
    k_scan1  <<<NSCAN_BLOCKS, 256, 0, stream>>>(segend, bs);
    k_scan2  <<<1, 256, 0, stream>>>(bs);
    k_scan3  <<<(NBINS + 255) / 256, 256, 0, stream>>>(segend, bs);
    k_scatter<<<(E_EDGES + 255) / 256, 256, 0, stream>>>(src, dst, ety, nrm, segend, es);
    k_layer  <<<NT_BLOCKS, 512, 0, stream>>>(hA, es, segend, wfrag1, lwfrag1, b1, hB);
    k_layer  <<<NT_BLOCKS, 512, 0, stream>>>(hB, es, segend, wfrag2, lwfrag2, b2, hA);
    k_mlp    <<<NPAIRS / 16, 512, 0, stream>>>(hA, drugs, targets, fc1frag, fc1b, fc2W, fc2b, outp);
}

// Round 5
// 370.201 us; speedup vs baseline: 3.3086x; 1.3798x over previous
//
#include <hip/hip_runtime.h>
#include <math.h>

typedef __attribute__((ext_vector_type(8))) short short8;
typedef __attribute__((ext_vector_type(4))) float f32x4;

#define N_SUBN   20000
#define E_EDGES  400000
#define R_REL    16
#define H_DIM    256
#define NBINS    (N_SUBN * R_REL)          // 320000 (dst,rel) buckets
#define SCAN_CHUNK 2048
#define NSCAN_BLOCKS ((NBINS + SCAN_CHUNK - 1) / SCAN_CHUNK)   // 157
#define NPAIRS   4096
#define TILE_N   32
#define NT_BLOCKS (N_SUBN / TILE_N)                            // 625 exact
#define D2       512

// ---- bf16 hi/lo split helpers (RNE) ----
__device__ __forceinline__ ushort f2bf(float x) {
    uint u = __float_as_uint(x);
    u += 0x7fffu + ((u >> 16) & 1u);
    return (ushort)(u >> 16);
}
__device__ __forceinline__ float bf2f(ushort h) {
    return __uint_as_float(((uint)h) << 16);
}

// ---------------- gather: h0 = emb[node_ids] ----------------
__global__ void k_gather(const float* __restrict__ emb, const int* __restrict__ nid,
                         float* __restrict__ h0) {
    int t = blockIdx.x * blockDim.x + threadIdx.x;   // 20000*64 float4 slots
    int node = t >> 6, c = (t & 63) << 2;
    if (node >= N_SUBN) return;
    const float4 s = *reinterpret_cast<const float4*>(emb + (size_t)nid[node] * H_DIM + c);
    *reinterpret_cast<float4*>(h0 + (size_t)node * H_DIM + c) = s;
}

// ---------------- CSR build over bin = dst*R + etype ----------------
__global__ void k_count(const int* __restrict__ dst, const int* __restrict__ ety,
                        int* __restrict__ cnt) {
    int e = blockIdx.x * 256 + threadIdx.x;
    if (e < E_EDGES) atomicAdd(&cnt[dst[e] * R_REL + ety[e]], 1);
}

__global__ void k_scan1(int* __restrict__ data, int* __restrict__ bs) {
    __shared__ int ts[256];
    int base = blockIdx.x * SCAN_CHUNK + threadIdx.x * 8;
    int v[8]; int s = 0;
#pragma unroll
    for (int j = 0; j < 8; j++) {
        int idx = base + j;
        v[j] = (idx < NBINS) ? data[idx] : 0;
        s += v[j];
    }
    ts[threadIdx.x] = s;
    __syncthreads();
    for (int off = 1; off < 256; off <<= 1) {
        int add = (threadIdx.x >= (unsigned)off) ? ts[threadIdx.x - off] : 0;
        __syncthreads();
        ts[threadIdx.x] += add;
        __syncthreads();
    }
    int excl = ts[threadIdx.x] - s;
    if (threadIdx.x == 255) bs[blockIdx.x] = ts[255];
    int run = excl;
#pragma unroll
    for (int j = 0; j < 8; j++) {
        int idx = base + j;
        if (idx < NBINS) data[idx] = run;
        run += v[j];
    }
}

__global__ void k_scan2(int* __restrict__ bs) {
    __shared__ int ls[NSCAN_BLOCKS];
    if (threadIdx.x < NSCAN_BLOCKS) ls[threadIdx.x] = bs[threadIdx.x];
    __syncthreads();
    if (threadIdx.x == 0) {
        int run = 0;
        for (int i = 0; i < NSCAN_BLOCKS; i++) { int t = ls[i]; ls[i] = run; run += t; }
    }
    __syncthreads();
    if (threadIdx.x < NSCAN_BLOCKS) bs[threadIdx.x] = ls[threadIdx.x];
}

__global__ void k_scan3(int* __restrict__ data, const int* __restrict__ bs) {
    int idx = blockIdx.x * 256 + threadIdx.x;
    if (idx < NBINS) data[idx] = data[idx] + bs[idx / SCAN_CHUNK];
}

// scatter increments segend in place: post-scatter segend[bin] = END of bin,
// beg(bin) = (bin==0) ? 0 : segend[bin-1]. Edge packed: (src<<17) | norm_q17.
__global__ void k_scatter(const int* __restrict__ src, const int* __restrict__ dst,
                          const int* __restrict__ ety, const float* __restrict__ nrm,
                          int* __restrict__ segend, uint* __restrict__ es) {
    int e = blockIdx.x * 256 + threadIdx.x;
    if (e >= E_EDGES) return;
    int bin = dst[e] * R_REL + ety[e];
    int pos = atomicAdd(&segend[bin], 1);
    float n = nrm[e];
    uint q = (uint)fminf(n * 131072.f + 0.5f, 131071.f);
    es[pos] = ((uint)src[e] << 17) | q;
}

// ---------------- W fragment pre-pack (bf16 hi/lo, MFMA B-layout) ----------------
__global__ void k_prep_w(const float* __restrict__ w, ushort* __restrict__ wfrag) {
    int t = blockIdx.x * 256 + threadIdx.x;   // 256 frags * 64 lanes = 16384
    int lane = t & 63, f = t >> 6;
    int ot = f & 1, rb = f >> 1;              // rb = r*8+b
    int kbase = (lane >> 4) * 8, n = ot * 16 + (lane & 15);
    ushort hv[8], lv[8];
#pragma unroll
    for (int j = 0; j < 8; j++) {
        float x = w[(size_t)(rb * 32 + kbase + j) * 32 + n];
        ushort h = f2bf(x);
        ushort l = f2bf(x - bf2f(h));
        hv[j] = h; lv[j] = l;
    }
    *reinterpret_cast<short8*>(wfrag + ((size_t)(f * 2 + 0) * 64 + lane) * 8) =
        *reinterpret_cast<short8*>(hv);
    *reinterpret_cast<short8*>(wfrag + ((size_t)(f * 2 + 1) * 64 + lane) * 8) =
        *reinterpret_cast<short8*>(lv);
}

// lwfrag: frag g = kt*16+ot (kt 0..7, ot 0..15)
__global__ void k_prep_lw(const float* __restrict__ lw, ushort* __restrict__ lwfrag) {
    int t = blockIdx.x * 256 + threadIdx.x;   // 128 frags * 64 lanes = 8192
    int lane = t & 63, g = t >> 6;
    int kt = g >> 4, ot = g & 15;
    int kbase = kt * 32 + (lane >> 4) * 8, n = ot * 16 + (lane & 15);
    ushort hv[8], lv[8];
#pragma unroll
    for (int j = 0; j < 8; j++) {
        float x = lw[(size_t)(kbase + j) * H_DIM + n];
        ushort h = f2bf(x);
        ushort l = f2bf(x - bf2f(h));
        hv[j] = h; lv[j] = l;
    }
    *reinterpret_cast<short8*>(lwfrag + ((size_t)(g * 2 + 0) * 64 + lane) * 8) =
        *reinterpret_cast<short8*>(hv);
    *reinterpret_cast<short8*>(lwfrag + ((size_t)(g * 2 + 1) * 64 + lane) * 8) =
        *reinterpret_cast<short8*>(lv);
}

// fc1frag: frag g = kt*32+ot (kt 0..15, ot 0..31)
__global__ void k_prep_fc1(const float* __restrict__ w, ushort* __restrict__ wfrag) {
    int t = blockIdx.x * 256 + threadIdx.x;   // 512 frags * 64 lanes = 32768
    int lane = t & 63, g = t >> 6;
    int kt = g >> 5, ot = g & 31;
    int kbase = kt * 32 + (lane >> 4) * 8, n = ot * 16 + (lane & 15);
    ushort hv[8], lv[8];
#pragma unroll
    for (int j = 0; j < 8; j++) {
        float x = w[(size_t)(kbase + j) * D2 + n];
        ushort h = f2bf(x);
        ushort l = f2bf(x - bf2f(h));
        hv[j] = h; lv[j] = l;
    }
    *reinterpret_cast<short8*>(wfrag + ((size_t)(g * 2 + 0) * 64 + lane) * 8) =
        *reinterpret_cast<short8*>(hv);
    *reinterpret_cast<short8*>(wfrag + ((size_t)(g * 2 + 1) * 64 + lane) * 8) =
        *reinterpret_cast<short8*>(lv);
}

// ---------------- fused RGCN-BDD layer (MFMA, bf16 hi/lo 3-term) ----------------
// block = 32 dst nodes, 256 threads = 4 waves. Wave wv owns output cols
// 64wv..64wv+63 (b-blocks 2wv,2wv+1) across 2 m-tiles. Per relation: each wave
// aggregates 8 nodes via 2-way interleaved edge cursors (2 independent load
// chains); bin offsets come from a block-local LDS table (no dependent global
// loads). LDS planes XOR-swizzled. 34 KB LDS -> 4 blocks/CU.
__global__ __launch_bounds__(256) void k_layer(
    const float* __restrict__ hin, const uint* __restrict__ es, const int* __restrict__ segend,
    const ushort* __restrict__ wfrag, const ushort* __restrict__ lwfrag,
    const float* __restrict__ bias, float* __restrict__ hout) {
    __shared__ __align__(16) ushort aggH[TILE_N * H_DIM];
    __shared__ __align__(16) ushort aggLo[TILE_N * H_DIM];
    __shared__ int lofs[TILE_N * R_REL + 1];    // lofs[j]=beg of local bin j; [j+1]=end
    char* cH = (char*)aggH;
    char* cL = (char*)aggLo;
    const int n0 = blockIdx.x * TILE_N;
    const int tid = threadIdx.x;
    const int lane = tid & 63, wv = tid >> 6;
    const int col = lane & 15, kg = lane >> 4;
    const short8* wf  = (const short8*)wfrag;
    const short8* lwf = (const short8*)lwfrag;

    {   // block-local offset table (coalesced, once)
        const int base = n0 * R_REL;
        for (int j = tid; j < TILE_N * R_REL + 1; j += 256) {
            int g = base + j - 1;
            lofs[j] = (g < 0) ? 0 : segend[g];
        }
    }

    f32x4 acc[2][4];
#pragma unroll
    for (int mt = 0; mt < 2; ++mt)
#pragma unroll
        for (int oi = 0; oi < 4; ++oi) acc[mt][oi] = (f32x4){0.f, 0.f, 0.f, 0.f};

    const uint laneoff = (uint)(lane << 2);

    for (int r = 0; r < R_REL; ++r) {
        __syncthreads();   // lofs ready (r=0) / previous MFMA reads done
#pragma unroll
        for (int ii = 0; ii < 8; ii += 2) {
            const int tA = 8 * wv + ii, tB = tA + 1;
            int eA = lofs[tA * R_REL + r], endA = lofs[tA * R_REL + r + 1];
            int eB = lofs[tB * R_REL + r], endB = lofs[tB * R_REL + r + 1];
            float4 aA = make_float4(0.f, 0.f, 0.f, 0.f);
            float4 aB = make_float4(0.f, 0.f, 0.f, 0.f);
            while (eA < endA && eB < endB) {     // two independent load chains
                uint pA = es[eA], pB = es[eB];
                float nA = (float)(pA & 0x1FFFFu) * (1.f / 131072.f);
                float nB = (float)(pB & 0x1FFFFu) * (1.f / 131072.f);
                const float4 xA = *reinterpret_cast<const float4*>(
                    hin + (size_t)(pA >> 17) * H_DIM + laneoff);
                const float4 xB = *reinterpret_cast<const float4*>(
                    hin + (size_t)(pB >> 17) * H_DIM + laneoff);
                aA.x = fmaf(xA.x, nA, aA.x); aA.y = fmaf(xA.y, nA, aA.y);
                aA.z = fmaf(xA.z, nA, aA.z); aA.w = fmaf(xA.w, nA, aA.w);
                aB.x = fmaf(xB.x, nB, aB.x); aB.y = fmaf(xB.y, nB, aB.y);
                aB.z = fmaf(xB.z, nB, aB.z); aB.w = fmaf(xB.w, nB, aB.w);
                ++eA; ++eB;
            }
            while (eA < endA) {
                uint pA = es[eA++];
                float nA = (float)(pA & 0x1FFFFu) * (1.f / 131072.f);
                const float4 xA = *reinterpret_cast<const float4*>(
                    hin + (size_t)(pA >> 17) * H_DIM + laneoff);
                aA.x = fmaf(xA.x, nA, aA.x); aA.y = fmaf(xA.y, nA, aA.y);
                aA.z = fmaf(xA.z, nA, aA.z); aA.w = fmaf(xA.w, nA, aA.w);
            }
            while (eB < endB) {
                uint pB = es[eB++];
                float nB = (float)(pB & 0x1FFFFu) * (1.f / 131072.f);
                const float4 xB = *reinterpret_cast<const float4*>(
                    hin + (size_t)(pB >> 17) * H_DIM + laneoff);
                aB.x = fmaf(xB.x, nB, aB.x); aB.y = fmaf(xB.y, nB, aB.y);
                aB.z = fmaf(xB.z, nB, aB.z); aB.w = fmaf(xB.w, nB, aB.w);
            }
            {   // split+store A
                ushort h0 = f2bf(aA.x), h1 = f2bf(aA.y), h2 = f2bf(aA.z), h3 = f2bf(aA.w);
                uint2 ph = make_uint2((uint)h0 | ((uint)h1 << 16), (uint)h2 | ((uint)h3 << 16));
                uint2 pl = make_uint2(
                    (uint)f2bf(aA.x - bf2f(h0)) | ((uint)f2bf(aA.y - bf2f(h1)) << 16),
                    (uint)f2bf(aA.z - bf2f(h2)) | ((uint)f2bf(aA.w - bf2f(h3)) << 16));
                uint byte = (uint)(tA * 512) +
                            ((((lane >> 1) ^ (tA & 7)) << 4) | ((lane & 1) << 3));
                *(uint2*)(cH + byte) = ph;
                *(uint2*)(cL + byte) = pl;
            }
            {   // split+store B
                ushort h0 = f2bf(aB.x), h1 = f2bf(aB.y), h2 = f2bf(aB.z), h3 = f2bf(aB.w);
                uint2 ph = make_uint2((uint)h0 | ((uint)h1 << 16), (uint)h2 | ((uint)h3 << 16));
                uint2 pl = make_uint2(
                    (uint)f2bf(aB.x - bf2f(h0)) | ((uint)f2bf(aB.y - bf2f(h1)) << 16),
                    (uint)f2bf(aB.z - bf2f(h2)) | ((uint)f2bf(aB.w - bf2f(h3)) << 16));
                uint byte = (uint)(tB * 512) +
                            ((((lane >> 1) ^ (tB & 7)) << 4) | ((lane & 1) << 3));
                *(uint2*)(cH + byte) = ph;
                *(uint2*)(cL + byte) = pl;
            }
        }
        __syncthreads();
#pragma unroll
        for (int bi = 0; bi < 2; ++bi) {
            int b = 2 * wv + bi;
#pragma unroll
            for (int ot = 0; ot < 2; ++ot) {
                int f = (r * 8 + b) * 2 + ot;
                short8 Bh = wf[(f * 2 + 0) * 64 + lane];
                short8 Bl = wf[(f * 2 + 1) * 64 + lane];
#pragma unroll
                for (int mt = 0; mt < 2; ++mt) {
                    int row = mt * 16 + col;
                    uint ab = (uint)(row * 512) + ((uint)((b * 4 + kg) ^ (row & 7)) << 4);
                    short8 Ah = *(const short8*)(cH + ab);
                    short8 Al = *(const short8*)(cL + ab);
                    f32x4 a = acc[mt][bi * 2 + ot];
                    a = __builtin_amdgcn_mfma_f32_16x16x32_bf16(Ah, Bh, a, 0, 0, 0);
                    a = __builtin_amdgcn_mfma_f32_16x16x32_bf16(Ah, Bl, a, 0, 0, 0);
                    a = __builtin_amdgcn_mfma_f32_16x16x32_bf16(Al, Bh, a, 0, 0, 0);
                    acc[mt][bi * 2 + ot] = a;
                }
            }
        }
    }

    // ---- self-loop: restage h tile as hi/lo, K=256 MFMA sweep ----
    __syncthreads();
    for (int i = 0; i < 8; ++i) {
        int t = 8 * wv + i;
        const float4 xv = *reinterpret_cast<const float4*>(
            hin + (size_t)(n0 + t) * H_DIM + laneoff);
        ushort h0 = f2bf(xv.x), h1 = f2bf(xv.y), h2 = f2bf(xv.z), h3 = f2bf(xv.w);
        uint2 ph = make_uint2((uint)h0 | ((uint)h1 << 16), (uint)h2 | ((uint)h3 << 16));
        uint2 pl = make_uint2(
            (uint)f2bf(xv.x - bf2f(h0)) | ((uint)f2bf(xv.y - bf2f(h1)) << 16),
            (uint)f2bf(xv.z - bf2f(h2)) | ((uint)f2bf(xv.w - bf2f(h3)) << 16));
        uint byte = (uint)(t * 512) + ((((lane >> 1) ^ (t & 7)) << 4) | ((lane & 1) << 3));
        *(uint2*)(cH + byte) = ph;
        *(uint2*)(cL + byte) = pl;
    }
    __syncthreads();
#pragma unroll
    for (int kt = 0; kt < 8; ++kt) {
#pragma unroll
        for (int oi = 0; oi < 4; ++oi) {
            int g = kt * 16 + 4 * wv + oi;
            short8 Bh = lwf[(g * 2 + 0) * 64 + lane];
            short8 Bl = lwf[(g * 2 + 1) * 64 + lane];
#pragma unroll
            for (int mt = 0; mt < 2; ++mt) {
                int row = mt * 16 + col;
                uint ab = (uint)(row * 512) + ((uint)((kt * 4 + kg) ^ (row & 7)) << 4);
                short8 Ah = *(const short8*)(cH + ab);
                short8 Al = *(const short8*)(cL + ab);
                f32x4 a = acc[mt][oi];
                a = __builtin_amdgcn_mfma_f32_16x16x32_bf16(Ah, Bh, a, 0, 0, 0);
                a = __builtin_amdgcn_mfma_f32_16x16x32_bf16(Ah, Bl, a, 0, 0, 0);
                a = __builtin_amdgcn_mfma_f32_16x16x32_bf16(Al, Bh, a, 0, 0, 0);
                acc[mt][oi] = a;
            }
        }
    }

    // ---- epilogue: C/D layout col=lane&15, row=(lane>>4)*4+reg ----
#pragma unroll
    for (int mt = 0; mt < 2; ++mt) {
        int nbase = n0 + mt * 16 + kg * 4;
#pragma unroll
        for (int oi = 0; oi < 4; ++oi) {
            int o = 64 * wv + oi * 16 + col;
            float bo = bias[o];
#pragma unroll
            for (int rg = 0; rg < 4; ++rg)
                hout[(size_t)(nbase + rg) * H_DIM + o] = acc[mt][oi][rg] + bo;
        }
    }
}

// ---------------- fused concat + fc1(MFMA) + relu + fc2 + sigmoid ----------------
__global__ __launch_bounds__(512) void k_mlp(
    const float* __restrict__ h, const int* __restrict__ drugs, const int* __restrict__ targets,
    const ushort* __restrict__ fc1frag, const float* __restrict__ b1f,
    const float* __restrict__ W2, const float* __restrict__ b2f,
    float* __restrict__ outp) {
    __shared__ __align__(16) ushort xH[16 * D2];
    __shared__ __align__(16) ushort xL[16 * D2];
    __shared__ float red[16][8];
    char* cH = (char*)xH;
    char* cL = (char*)xL;
    const int tid = threadIdx.x;
    const int lane = tid & 63, wv = tid >> 6;
    const int col = lane & 15, kg = lane >> 4;
    const int p0 = blockIdx.x * 16;
    const short8* wf = (const short8*)fc1frag;

    {   // stage X = [h[drug] | h[target]] as bf16 hi/lo, swizzled
        int p = tid >> 5;
        int cc = (tid & 31) * 16;
        int di = drugs[p0 + p], ti = targets[p0 + p];
        const float* srcp = (cc < H_DIM) ? (h + (size_t)di * H_DIM + cc)
                                         : (h + (size_t)ti * H_DIM + (cc - H_DIM));
#pragma unroll
        for (int j = 0; j < 2; ++j) {
            float4 a = *reinterpret_cast<const float4*>(srcp + j * 8);
            float4 b = *reinterpret_cast<const float4*>(srcp + j * 8 + 4);
            float f[8] = {a.x, a.y, a.z, a.w, b.x, b.y, b.z, b.w};
            short8 hv, lv;
#pragma unroll
            for (int q = 0; q < 8; ++q) {
                ushort hh = f2bf(f[q]);
                hv[q] = (short)hh;
                lv[q] = (short)f2bf(f[q] - bf2f(hh));
            }
            uint chunk = (uint)((tid & 31) * 2 + j);
            uint byte = (uint)p * 1024 + ((chunk ^ (uint)(p & 7)) << 4);
            *(short8*)(cH + byte) = hv;
            *(short8*)(cL + byte) = lv;
        }
    }
    __syncthreads();

    f32x4 acc[4];
#pragma unroll
    for (int oi = 0; oi < 4; ++oi) acc[oi] = (f32x4){0.f, 0.f, 0.f, 0.f};

    for (int kt = 0; kt < 16; ++kt) {
        uint ab = (uint)col * 1024 + ((uint)((kt * 4 + kg) ^ (col & 7)) << 4);
        short8 Ah = *(const short8*)(cH + ab);
        short8 Al = *(const short8*)(cL + ab);
#pragma unroll
        for (int oi = 0; oi < 4; ++oi) {
            int g = kt * 32 + wv * 4 + oi;
            short8 Bh = wf[(g * 2 + 0) * 64 + lane];
            short8 Bl = wf[(g * 2 + 1) * 64 + lane];
            f32x4 a = acc[oi];
            a = __builtin_amdgcn_mfma_f32_16x16x32_bf16(Ah, Bh, a, 0, 0, 0);
            a = __builtin_amdgcn_mfma_f32_16x16x32_bf16(Ah, Bl, a, 0, 0, 0);
            a = __builtin_amdgcn_mfma_f32_16x16x32_bf16(Al, Bh, a, 0, 0, 0);
            a = __builtin_amdgcn_mfma_f32_16x16x32_bf16(Al, Bl, a, 0, 0, 0);
            acc[oi] = a;
        }
    }

    float val[4] = {0.f, 0.f, 0.f, 0.f};
#pragma unroll
    for (int oi = 0; oi < 4; ++oi) {
        int o = 64 * wv + oi * 16 + col;
        float b1o = b1f[o], w2o = W2[o];
#pragma unroll
        for (int rg = 0; rg < 4; ++rg) {
            float y = acc[oi][rg] + b1o;
            y = y > 0.f ? y : 0.f;
            val[rg] = fmaf(y, w2o, val[rg]);
        }
    }
#pragma unroll
    for (int rg = 0; rg < 4; ++rg) {
        float v = val[rg];
        v += __shfl_xor(v, 1, 64);
        v += __shfl_xor(v, 2, 64);
        v += __shfl_xor(v, 4, 64);
        v += __shfl_xor(v, 8, 64);
        val[rg] = v;
    }
    if (col == 0) {
#pragma unroll
        for (int rg = 0; rg < 4; ++rg) red[kg * 4 + rg][wv] = val[rg];
    }
    __syncthreads();
    if (tid < 16) {
        float s = 0.f;
#pragma unroll
        for (int w = 0; w < 8; w++) s += red[tid][w];
        s += b2f[0];
        outp[p0 + tid] = 1.f / (1.f + __expf(-s));
    }
}

extern "C" void kernel_launch(void* const* d_in, const int* in_sizes, int n_in,
                              void* d_out, int out_size, void* d_ws, size_t ws_size,
                              hipStream_t stream) {
    (void)in_sizes; (void)n_in; (void)out_size; (void)ws_size;
    const int*   drugs   = (const int*)d_in[0];
    const int*   targets = (const int*)d_in[1];
    const int*   nid     = (const int*)d_in[2];
    const int*   src     = (const int*)d_in[3];
    const int*   dst     = (const int*)d_in[4];
    const int*   ety     = (const int*)d_in[5];
    const float* nrm     = (const float*)d_in[6];
    const float* emb     = (const float*)d_in[7];
    const float* w1      = (const float*)d_in[8];
    const float* lw1     = (const float*)d_in[9];
    const float* b1      = (const float*)d_in[10];
    const float* w2      = (const float*)d_in[11];
    const float* lw2     = (const float*)d_in[12];
    const float* b2      = (const float*)d_in[13];
    const float* fc1W    = (const float*)d_in[14];
    const float* fc1b    = (const float*)d_in[15];
    const float* fc2W    = (const float*)d_in[16];
    const float* fc2b    = (const float*)d_in[17];
    float* outp = (float*)d_out;

    // ws layout — total 46,462,464 B (within proven budget).
    char* ws = (char*)d_ws;
    ushort* wfrag1  = (ushort*)(ws);                    //    524,288
    ushort* wfrag2  = (ushort*)(ws + 524288);           //    524,288
    ushort* lwfrag1 = (ushort*)(ws + 1048576);          //    262,144
    ushort* lwfrag2 = (ushort*)(ws + 1310720);          //    262,144
    ushort* fc1frag = (ushort*)(ws + 1572864);          //  1,048,576
    float*  hA      = (float*) (ws + 2621440);          // 20,480,000
    float*  hB      = (float*) (ws + 23101440);         // 20,480,000
    int*    segend  = (int*)   (ws + 43581440);         //  1,280,000
    int*    bs      = (int*)   (ws + 44861440);         //      1,024
    uint*   es      = (uint*)  (ws + 44862464);         //  1,600,000 -> end 46,462,464

    hipMemsetAsync(segend, 0, NBINS * sizeof(int), stream);
    k_prep_w  <<<64, 256, 0, stream>>>(w1, wfrag1);
    k_prep_w  <<<64, 256, 0, stream>>>(w2, wfrag2);
    k_prep_lw <<<32, 256, 0, stream>>>(lw1, lwfrag1);
    k_prep_lw <<<32, 256, 0, stream>>>(lw2, lwfrag2);
    k_prep_fc1<<<128, 256, 0, stream>>>(fc1W, fc1frag);
    k_gather <<<5000, 256, 0, stream>>>(emb, nid, hA);
    k_count  <<<(E_EDGES + 255) / 256, 256, 0, stream>>>(dst, ety, segend);
    k_scan1  <<<NSCAN_BLOCKS, 256, 0, stream>>>(segend, bs);
    k_scan2  <<<1, 256, 0, stream>>>(bs);
    k_scan3  <<<(NBINS + 255) / 256, 256, 0, stream>>>(segend, bs);
    k_scatter<<<(E_EDGES + 255) / 256, 256, 0, stream>>>(src, dst, ety, nrm, segend, es);
    k_layer  <<<NT_BLOCKS, 256, 0, stream>>>(hA, es, segend, wfrag1, lwfrag1, b1, hB);
    k_layer  <<<NT_BLOCKS, 256, 0, stream>>>(hB, es, segend, wfrag2, lwfrag2, b2, hA);
    k_mlp    <<<NPAIRS / 16, 512, 0, stream>>>(hA, drugs, targets, fc1frag, fc1b, fc2W, fc2b, outp);
}

// Round 6
// 304.018 us; speedup vs baseline: 4.0289x; 1.2177x over previous
//
#include <hip/hip_runtime.h>
#include <math.h>

typedef __attribute__((ext_vector_type(8))) short short8;
typedef __attribute__((ext_vector_type(4))) float f32x4;

#define N_SUBN   20000
#define E_EDGES  400000
#define R_REL    16
#define H_DIM    256
#define NBINS    (N_SUBN * R_REL)          // 320000 (dst,rel) buckets
#define SCAN_CHUNK 2048
#define NSCAN_BLOCKS ((NBINS + SCAN_CHUNK - 1) / SCAN_CHUNK)   // 157
#define NPAIRS   4096
#define TILE_N   32
#define NT_BLOCKS (N_SUBN / TILE_N)                            // 625 exact
#define D2       512

// ---- bf16 hi/lo split helpers (RNE) ----
__device__ __forceinline__ ushort f2bf(float x) {
    uint u = __float_as_uint(x);
    u += 0x7fffu + ((u >> 16) & 1u);
    return (ushort)(u >> 16);
}
__device__ __forceinline__ float bf2f(ushort h) {
    return __uint_as_float(((uint)h) << 16);
}

// ---------------- gather: h0 = emb[node_ids] ----------------
__global__ void k_gather(const float* __restrict__ emb, const int* __restrict__ nid,
                         float* __restrict__ h0) {
    int t = blockIdx.x * blockDim.x + threadIdx.x;   // 20000*64 float4 slots
    int node = t >> 6, c = (t & 63) << 2;
    if (node >= N_SUBN) return;
    const float4 s = *reinterpret_cast<const float4*>(emb + (size_t)nid[node] * H_DIM + c);
    *reinterpret_cast<float4*>(h0 + (size_t)node * H_DIM + c) = s;
}

// ---------------- CSR build over bin = dst*R + etype ----------------
__global__ void k_count(const int* __restrict__ dst, const int* __restrict__ ety,
                        int* __restrict__ cnt) {
    int e = blockIdx.x * 256 + threadIdx.x;
    if (e < E_EDGES) atomicAdd(&cnt[dst[e] * R_REL + ety[e]], 1);
}

__global__ void k_scan1(int* __restrict__ data, int* __restrict__ bs) {
    __shared__ int ts[256];
    int base = blockIdx.x * SCAN_CHUNK + threadIdx.x * 8;
    int v[8]; int s = 0;
#pragma unroll
    for (int j = 0; j < 8; j++) {
        int idx = base + j;
        v[j] = (idx < NBINS) ? data[idx] : 0;
        s += v[j];
    }
    ts[threadIdx.x] = s;
    __syncthreads();
    for (int off = 1; off < 256; off <<= 1) {
        int add = (threadIdx.x >= (unsigned)off) ? ts[threadIdx.x - off] : 0;
        __syncthreads();
        ts[threadIdx.x] += add;
        __syncthreads();
    }
    int excl = ts[threadIdx.x] - s;
    if (threadIdx.x == 255) bs[blockIdx.x] = ts[255];
    int run = excl;
#pragma unroll
    for (int j = 0; j < 8; j++) {
        int idx = base + j;
        if (idx < NBINS) data[idx] = run;
        run += v[j];
    }
}

__global__ void k_scan2(int* __restrict__ bs) {
    __shared__ int ls[NSCAN_BLOCKS];
    if (threadIdx.x < NSCAN_BLOCKS) ls[threadIdx.x] = bs[threadIdx.x];
    __syncthreads();
    if (threadIdx.x == 0) {
        int run = 0;
        for (int i = 0; i < NSCAN_BLOCKS; i++) { int t = ls[i]; ls[i] = run; run += t; }
    }
    __syncthreads();
    if (threadIdx.x < NSCAN_BLOCKS) bs[threadIdx.x] = ls[threadIdx.x];
}

__global__ void k_scan3(int* __restrict__ data, const int* __restrict__ bs) {
    int idx = blockIdx.x * 256 + threadIdx.x;
    if (idx < NBINS) data[idx] = data[idx] + bs[idx / SCAN_CHUNK];
}

// scatter increments segend in place: post-scatter segend[bin] = END of bin,
// beg(bin) = (bin==0) ? 0 : segend[bin-1]. Edge packed: (src<<17) | norm_q17.
__global__ void k_scatter(const int* __restrict__ src, const int* __restrict__ dst,
                          const int* __restrict__ ety, const float* __restrict__ nrm,
                          int* __restrict__ segend, uint* __restrict__ es) {
    int e = blockIdx.x * 256 + threadIdx.x;
    if (e >= E_EDGES) return;
    int bin = dst[e] * R_REL + ety[e];
    int pos = atomicAdd(&segend[bin], 1);
    float n = nrm[e];
    uint q = (uint)fminf(n * 131072.f + 0.5f, 131071.f);
    es[pos] = ((uint)src[e] << 17) | q;
}

// ---------------- W fragment pre-pack (bf16 hi/lo, MFMA B-layout) ----------------
__global__ void k_prep_w(const float* __restrict__ w, ushort* __restrict__ wfrag) {
    int t = blockIdx.x * 256 + threadIdx.x;   // 256 frags * 64 lanes = 16384
    int lane = t & 63, f = t >> 6;
    int ot = f & 1, rb = f >> 1;              // rb = r*8+b
    int kbase = (lane >> 4) * 8, n = ot * 16 + (lane & 15);
    ushort hv[8], lv[8];
#pragma unroll
    for (int j = 0; j < 8; j++) {
        float x = w[(size_t)(rb * 32 + kbase + j) * 32 + n];
        ushort h = f2bf(x);
        ushort l = f2bf(x - bf2f(h));
        hv[j] = h; lv[j] = l;
    }
    *reinterpret_cast<short8*>(wfrag + ((size_t)(f * 2 + 0) * 64 + lane) * 8) =
        *reinterpret_cast<short8*>(hv);
    *reinterpret_cast<short8*>(wfrag + ((size_t)(f * 2 + 1) * 64 + lane) * 8) =
        *reinterpret_cast<short8*>(lv);
}

// lwfrag: frag g = kt*16+ot (kt 0..7, ot 0..15)
__global__ void k_prep_lw(const float* __restrict__ lw, ushort* __restrict__ lwfrag) {
    int t = blockIdx.x * 256 + threadIdx.x;   // 128 frags * 64 lanes = 8192
    int lane = t & 63, g = t >> 6;
    int kt = g >> 4, ot = g & 15;
    int kbase = kt * 32 + (lane >> 4) * 8, n = ot * 16 + (lane & 15);
    ushort hv[8], lv[8];
#pragma unroll
    for (int j = 0; j < 8; j++) {
        float x = lw[(size_t)(kbase + j) * H_DIM + n];
        ushort h = f2bf(x);
        ushort l = f2bf(x - bf2f(h));
        hv[j] = h; lv[j] = l;
    }
    *reinterpret_cast<short8*>(lwfrag + ((size_t)(g * 2 + 0) * 64 + lane) * 8) =
        *reinterpret_cast<short8*>(hv);
    *reinterpret_cast<short8*>(lwfrag + ((size_t)(g * 2 + 1) * 64 + lane) * 8) =
        *reinterpret_cast<short8*>(lv);
}

// fc1frag: frag g = kt*32+ot (kt 0..15, ot 0..31)
__global__ void k_prep_fc1(const float* __restrict__ w, ushort* __restrict__ wfrag) {
    int t = blockIdx.x * 256 + threadIdx.x;   // 512 frags * 64 lanes = 32768
    int lane = t & 63, g = t >> 6;
    int kt = g >> 5, ot = g & 31;
    int kbase = kt * 32 + (lane >> 4) * 8, n = ot * 16 + (lane & 15);
    ushort hv[8], lv[8];
#pragma unroll
    for (int j = 0; j < 8; j++) {
        float x = w[(size_t)(kbase + j) * D2 + n];
        ushort h = f2bf(x);
        ushort l = f2bf(x - bf2f(h));
        hv[j] = h; lv[j] = l;
    }
    *reinterpret_cast<short8*>(wfrag + ((size_t)(g * 2 + 0) * 64 + lane) * 8) =
        *reinterpret_cast<short8*>(hv);
    *reinterpret_cast<short8*>(wfrag + ((size_t)(g * 2 + 1) * 64 + lane) * 8) =
        *reinterpret_cast<short8*>(lv);
}

// ---------------- fused RGCN-BDD layer (MFMA, bf16 hi/lo 3-term) ----------------
// block = 32 dst nodes, 512 threads = 8 waves. Wave wv aggregates nodes
// 4wv..4wv+3 per relation via FOUR concurrently-interleaved edge cursors
// (wave-uniform branches -> scalar cbranch, 4 independent load chains).
// MFMA: wave wv owns b-block wv (output cols 32wv..32wv+31), acc[2][2].
__global__ __launch_bounds__(512) void k_layer(
    const float* __restrict__ hin, const uint* __restrict__ es, const int* __restrict__ segend,
    const ushort* __restrict__ wfrag, const ushort* __restrict__ lwfrag,
    const float* __restrict__ bias, float* __restrict__ hout) {
    __shared__ __align__(16) ushort aggH[TILE_N * H_DIM];
    __shared__ __align__(16) ushort aggLo[TILE_N * H_DIM];
    __shared__ int lofs[TILE_N * R_REL + 1];    // lofs[j]=beg of local bin j; [j+1]=end
    char* cH = (char*)aggH;
    char* cL = (char*)aggLo;
    const int n0 = blockIdx.x * TILE_N;
    const int tid = threadIdx.x;
    const int lane = tid & 63, wv = tid >> 6;
    const int col = lane & 15, kg = lane >> 4;
    const short8* wf  = (const short8*)wfrag;
    const short8* lwf = (const short8*)lwfrag;

    {   // block-local offset table (coalesced, once)
        const int base = n0 * R_REL;
        for (int j = tid; j < TILE_N * R_REL + 1; j += 512) {
            int g = base + j - 1;
            lofs[j] = (g < 0) ? 0 : segend[g];
        }
    }

    f32x4 acc[2][2];
#pragma unroll
    for (int mt = 0; mt < 2; ++mt)
#pragma unroll
        for (int ot = 0; ot < 2; ++ot) acc[mt][ot] = (f32x4){0.f, 0.f, 0.f, 0.f};

    const uint laneoff = (uint)(lane << 2);
    const int t0 = 4 * wv;

    for (int r = 0; r < R_REL; ++r) {
        __syncthreads();   // lofs ready (r=0) / previous MFMA reads done
        // ---- 4-way interleaved aggregation of nodes t0..t0+3 ----
        int e0 = lofs[(t0 + 0) * R_REL + r], d0 = lofs[(t0 + 0) * R_REL + r + 1];
        int e1 = lofs[(t0 + 1) * R_REL + r], d1 = lofs[(t0 + 1) * R_REL + r + 1];
        int e2 = lofs[(t0 + 2) * R_REL + r], d2 = lofs[(t0 + 2) * R_REL + r + 1];
        int e3 = lofs[(t0 + 3) * R_REL + r], d3 = lofs[(t0 + 3) * R_REL + r + 1];
        float4 a0 = make_float4(0.f, 0.f, 0.f, 0.f);
        float4 a1 = make_float4(0.f, 0.f, 0.f, 0.f);
        float4 a2 = make_float4(0.f, 0.f, 0.f, 0.f);
        float4 a3 = make_float4(0.f, 0.f, 0.f, 0.f);
        while ((e0 < d0) | (e1 < d1) | (e2 < d2) | (e3 < d3)) {
            bool g0 = e0 < d0, g1 = e1 < d1, g2 = e2 < d2, g3 = e3 < d3;
            uint p0 = 0, p1 = 0, p2 = 0, p3 = 0;
            if (g0) p0 = es[e0++];
            if (g1) p1 = es[e1++];
            if (g2) p2 = es[e2++];
            if (g3) p3 = es[e3++];
            if (g0) {
                const float4 x = *reinterpret_cast<const float4*>(
                    hin + (size_t)(p0 >> 17) * H_DIM + laneoff);
                float nm = (float)(p0 & 0x1FFFFu) * (1.f / 131072.f);
                a0.x = fmaf(x.x, nm, a0.x); a0.y = fmaf(x.y, nm, a0.y);
                a0.z = fmaf(x.z, nm, a0.z); a0.w = fmaf(x.w, nm, a0.w);
            }
            if (g1) {
                const float4 x = *reinterpret_cast<const float4*>(
                    hin + (size_t)(p1 >> 17) * H_DIM + laneoff);
                float nm = (float)(p1 & 0x1FFFFu) * (1.f / 131072.f);
                a1.x = fmaf(x.x, nm, a1.x); a1.y = fmaf(x.y, nm, a1.y);
                a1.z = fmaf(x.z, nm, a1.z); a1.w = fmaf(x.w, nm, a1.w);
            }
            if (g2) {
                const float4 x = *reinterpret_cast<const float4*>(
                    hin + (size_t)(p2 >> 17) * H_DIM + laneoff);
                float nm = (float)(p2 & 0x1FFFFu) * (1.f / 131072.f);
                a2.x = fmaf(x.x, nm, a2.x); a2.y = fmaf(x.y, nm, a2.y);
                a2.z = fmaf(x.z, nm, a2.z); a2.w = fmaf(x.w, nm, a2.w);
            }
            if (g3) {
                const float4 x = *reinterpret_cast<const float4*>(
                    hin + (size_t)(p3 >> 17) * H_DIM + laneoff);
                float nm = (float)(p3 & 0x1FFFFu) * (1.f / 131072.f);
                a3.x = fmaf(x.x, nm, a3.x); a3.y = fmaf(x.y, nm, a3.y);
                a3.z = fmaf(x.z, nm, a3.z); a3.w = fmaf(x.w, nm, a3.w);
            }
        }
#pragma unroll
        for (int i = 0; i < 4; ++i) {
            float4 av = (i == 0) ? a0 : (i == 1) ? a1 : (i == 2) ? a2 : a3;
            int t = t0 + i;
            ushort h0 = f2bf(av.x), h1 = f2bf(av.y), h2 = f2bf(av.z), h3 = f2bf(av.w);
            uint2 ph = make_uint2((uint)h0 | ((uint)h1 << 16), (uint)h2 | ((uint)h3 << 16));
            uint2 pl = make_uint2(
                (uint)f2bf(av.x - bf2f(h0)) | ((uint)f2bf(av.y - bf2f(h1)) << 16),
                (uint)f2bf(av.z - bf2f(h2)) | ((uint)f2bf(av.w - bf2f(h3)) << 16));
            uint byte = (uint)(t * 512) + ((((lane >> 1) ^ (t & 7)) << 4) | ((lane & 1) << 3));
            *(uint2*)(cH + byte) = ph;
            *(uint2*)(cL + byte) = pl;
        }
        __syncthreads();
        // ---- transform: wave wv owns b-block wv ----
#pragma unroll
        for (int ot = 0; ot < 2; ++ot) {
            int f = (r * 8 + wv) * 2 + ot;
            short8 Bh = wf[(f * 2 + 0) * 64 + lane];
            short8 Bl = wf[(f * 2 + 1) * 64 + lane];
#pragma unroll
            for (int mt = 0; mt < 2; ++mt) {
                int row = mt * 16 + col;
                uint ab = (uint)(row * 512) + ((uint)((wv * 4 + kg) ^ (row & 7)) << 4);
                short8 Ah = *(const short8*)(cH + ab);
                short8 Al = *(const short8*)(cL + ab);
                f32x4 a = acc[mt][ot];
                a = __builtin_amdgcn_mfma_f32_16x16x32_bf16(Ah, Bh, a, 0, 0, 0);
                a = __builtin_amdgcn_mfma_f32_16x16x32_bf16(Ah, Bl, a, 0, 0, 0);
                a = __builtin_amdgcn_mfma_f32_16x16x32_bf16(Al, Bh, a, 0, 0, 0);
                acc[mt][ot] = a;
            }
        }
    }

    // ---- self-loop: restage h tile as hi/lo, K=256 MFMA sweep ----
    __syncthreads();
#pragma unroll
    for (int i = 0; i < 4; ++i) {
        int t = t0 + i;
        const float4 xv = *reinterpret_cast<const float4*>(
            hin + (size_t)(n0 + t) * H_DIM + laneoff);
        ushort h0 = f2bf(xv.x), h1 = f2bf(xv.y), h2 = f2bf(xv.z), h3 = f2bf(xv.w);
        uint2 ph = make_uint2((uint)h0 | ((uint)h1 << 16), (uint)h2 | ((uint)h3 << 16));
        uint2 pl = make_uint2(
            (uint)f2bf(xv.x - bf2f(h0)) | ((uint)f2bf(xv.y - bf2f(h1)) << 16),
            (uint)f2bf(xv.z - bf2f(h2)) | ((uint)f2bf(xv.w - bf2f(h3)) << 16));
        uint byte = (uint)(t * 512) + ((((lane >> 1) ^ (t & 7)) << 4) | ((lane & 1) << 3));
        *(uint2*)(cH + byte) = ph;
        *(uint2*)(cL + byte) = pl;
    }
    __syncthreads();
#pragma unroll
    for (int kt = 0; kt < 8; ++kt) {
#pragma unroll
        for (int ot = 0; ot < 2; ++ot) {
            int g = kt * 16 + 2 * wv + ot;
            short8 Bh = lwf[(g * 2 + 0) * 64 + lane];
            short8 Bl = lwf[(g * 2 + 1) * 64 + lane];
#pragma unroll
            for (int mt = 0; mt < 2; ++mt) {
                int row = mt * 16 + col;
                uint ab = (uint)(row * 512) + ((uint)((kt * 4 + kg) ^ (row & 7)) << 4);
                short8 Ah = *(const short8*)(cH + ab);
                short8 Al = *(const short8*)(cL + ab);
                f32x4 a = acc[mt][ot];
                a = __builtin_amdgcn_mfma_f32_16x16x32_bf16(Ah, Bh, a, 0, 0, 0);
                a = __builtin_amdgcn_mfma_f32_16x16x32_bf16(Ah, Bl, a, 0, 0, 0);
                a = __builtin_amdgcn_mfma_f32_16x16x32_bf16(Al, Bh, a, 0, 0, 0);
                acc[mt][ot] = a;
            }
        }
    }

    // ---- epilogue: C/D layout col=lane&15, row=(lane>>4)*4+reg ----
#pragma unroll
    for (int mt = 0; mt < 2; ++mt) {
        int nbase = n0 + mt * 16 + kg * 4;
#pragma unroll
        for (int ot = 0; ot < 2; ++ot) {
            int o = 32 * wv + ot * 16 + col;
            float bo = bias[o];
#pragma unroll
            for (int rg = 0; rg < 4; ++rg)
                hout[(size_t)(nbase + rg) * H_DIM + o] = acc[mt][ot][rg] + bo;
        }
    }
}

// ---------------- fused concat + fc1(MFMA) + relu + fc2 + sigmoid ----------------
__global__ __launch_bounds__(512) void k_mlp(
    const float* __restrict__ h, const int* __restrict__ drugs, const int* __restrict__ targets,
    const ushort* __restrict__ fc1frag, const float* __restrict__ b1f,
    const float* __restrict__ W2, const float* __restrict__ b2f,
    float* __restrict__ outp) {
    __shared__ __align__(16) ushort xH[16 * D2];
    __shared__ __align__(16) ushort xL[16 * D2];
    __shared__ float red[16][8];
    char* cH = (char*)xH;
    char* cL = (char*)xL;
    const int tid = threadIdx.x;
    const int lane = tid & 63, wv = tid >> 6;
    const int col = lane & 15, kg = lane >> 4;
    const int p0 = blockIdx.x * 16;
    const short8* wf = (const short8*)fc1frag;

    {   // stage X = [h[drug] | h[target]] as bf16 hi/lo, swizzled
        int p = tid >> 5;
        int cc = (tid & 31) * 16;
        int di = drugs[p0 + p], ti = targets[p0 + p];
        const float* srcp = (cc < H_DIM) ? (h + (size_t)di * H_DIM + cc)
                                         : (h + (size_t)ti * H_DIM + (cc - H_DIM));
#pragma unroll
        for (int j = 0; j < 2; ++j) {
            float4 a = *reinterpret_cast<const float4*>(srcp + j * 8);
            float4 b = *reinterpret_cast<const float4*>(srcp + j * 8 + 4);
            float f[8] = {a.x, a.y, a.z, a.w, b.x, b.y, b.z, b.w};
            short8 hv, lv;
#pragma unroll
            for (int q = 0; q < 8; ++q) {
                ushort hh = f2bf(f[q]);
                hv[q] = (short)hh;
                lv[q] = (short)f2bf(f[q] - bf2f(hh));
            }
            uint chunk = (uint)((tid & 31) * 2 + j);
            uint byte = (uint)p * 1024 + ((chunk ^ (uint)(p & 7)) << 4);
            *(short8*)(cH + byte) = hv;
            *(short8*)(cL + byte) = lv;
        }
    }
    __syncthreads();

    f32x4 acc[4];
#pragma unroll
    for (int oi = 0; oi < 4; ++oi) acc[oi] = (f32x4){0.f, 0.f, 0.f, 0.f};

    for (int kt = 0; kt < 16; ++kt) {
        uint ab = (uint)col * 1024 + ((uint)((kt * 4 + kg) ^ (col & 7)) << 4);
        short8 Ah = *(const short8*)(cH + ab);
        short8 Al = *(const short8*)(cL + ab);
#pragma unroll
        for (int oi = 0; oi < 4; ++oi) {
            int g = kt * 32 + wv * 4 + oi;
            short8 Bh = wf[(g * 2 + 0) * 64 + lane];
            short8 Bl = wf[(g * 2 + 1) * 64 + lane];
            f32x4 a = acc[oi];
            a = __builtin_amdgcn_mfma_f32_16x16x32_bf16(Ah, Bh, a, 0, 0, 0);
            a = __builtin_amdgcn_mfma_f32_16x16x32_bf16(Ah, Bl, a, 0, 0, 0);
            a = __builtin_amdgcn_mfma_f32_16x16x32_bf16(Al, Bh, a, 0, 0, 0);
            a = __builtin_amdgcn_mfma_f32_16x16x32_bf16(Al, Bl, a, 0, 0, 0);
            acc[oi] = a;
        }
    }

    float val[4] = {0.f, 0.f, 0.f, 0.f};
#pragma unroll
    for (int oi = 0; oi < 4; ++oi) {
        int o = 64 * wv + oi * 16 + col;
        float b1o = b1f[o], w2o = W2[o];
#pragma unroll
        for (int rg = 0; rg < 4; ++rg) {
            float y = acc[oi][rg] + b1o;
            y = y > 0.f ? y : 0.f;
            val[rg] = fmaf(y, w2o, val[rg]);
        }
    }
#pragma unroll
    for (int rg = 0; rg < 4; ++rg) {
        float v = val[rg];
        v += __shfl_xor(v, 1, 64);
        v += __shfl_xor(v, 2, 64);
        v += __shfl_xor(v, 4, 64);
        v += __shfl_xor(v, 8, 64);
        val[rg] = v;
    }
    if (col == 0) {
#pragma unroll
        for (int rg = 0; rg < 4; ++rg) red[kg * 4 + rg][wv] = val[rg];
    }
    __syncthreads();
    if (tid < 16) {
        float s = 0.f;
#pragma unroll
        for (int w = 0; w < 8; w++) s += red[tid][w];
        s += b2f[0];
        outp[p0 + tid] = 1.f / (1.f + __expf(-s));
    }
}

extern "C" void kernel_launch(void* const* d_in, const int* in_sizes, int n_in,
                              void* d_out, int out_size, void* d_ws, size_t ws_size,
                              hipStream_t stream) {
    (void)in_sizes; (void)n_in; (void)out_size; (void)ws_size;
    const int*   drugs   = (const int*)d_in[0];
    const int*   targets = (const int*)d_in[1];
    const int*   nid     = (const int*)d_in[2];
    const int*   src     = (const int*)d_in[3];
    const int*   dst     = (const int*)d_in[4];
    const int*   ety     = (const int*)d_in[5];
    const float* nrm     = (const float*)d_in[6];
    const float* emb     = (const float*)d_in[7];
    const float* w1      = (const float*)d_in[8];
    const float* lw1     = (const float*)d_in[9];
    const float* b1      = (const float*)d_in[10];
    const float* w2      = (const float*)d_in[11];
    const float* lw2     = (const float*)d_in[12];
    const float* b2      = (const float*)d_in[13];
    const float* fc1W    = (const float*)d_in[14];
    const float* fc1b    = (const float*)d_in[15];
    const float* fc2W    = (const float*)d_in[16];
    const float* fc2b    = (const float*)d_in[17];
    float* outp = (float*)d_out;

    // ws layout — total 46,462,464 B (within proven budget).
    char* ws = (char*)d_ws;
    ushort* wfrag1  = (ushort*)(ws);                    //    524,288
    ushort* wfrag2  = (ushort*)(ws + 524288);           //    524,288
    ushort* lwfrag1 = (ushort*)(ws + 1048576);          //    262,144
    ushort* lwfrag2 = (ushort*)(ws + 1310720);          //    262,144
    ushort* fc1frag = (ushort*)(ws + 1572864);          //  1,048,576
    float*  hA      = (float*) (ws + 2621440);          // 20,480,000
    float*  hB      = (float*) (ws + 23101440);         // 20,480,000
    int*    segend  = (int*)   (ws + 43581440);         //  1,280,000
    int*    bs      = (int*)   (ws + 44861440);         //      1,024
    uint*   es      = (uint*)  (ws + 44862464);         //  1,600,000 -> end 46,462,464

    hipMemsetAsync(segend, 0, NBINS * sizeof(int), stream);
    k_prep_w  <<<64, 256, 0, stream>>>(w1, wfrag1);
    k_prep_w  <<<64, 256, 0, stream>>>(w2, wfrag2);
    k_prep_lw <<<32, 256, 0, stream>>>(lw1, lwfrag1);
    k_prep_lw <<<32, 256, 0, stream>>>(lw2, lwfrag2);
    k_prep_fc1<<<128, 256, 0, stream>>>(fc1W, fc1frag);
    k_gather <<<5000, 256, 0, stream>>>(emb, nid, hA);
    k_count  <<<(E_EDGES + 255) / 256, 256, 0, stream>>>(dst, ety, segend);
    k_scan1  <<<NSCAN_BLOCKS, 256, 0, stream>>>(segend, bs);
    k_scan2  <<<1, 256, 0, stream>>>(bs);
    k_scan3  <<<(NBINS + 255) / 256, 256, 0, stream>>>(segend, bs);
    k_scatter<<<(E_EDGES + 255) / 256, 256, 0, stream>>>(src, dst, ety, nrm, segend, es);
    k_layer  <<<NT_BLOCKS, 512, 0, stream>>>(hA, es, segend, wfrag1, lwfrag1, b1, hB);
    k_layer  <<<NT_BLOCKS, 512, 0, stream>>>(hB, es, segend, wfrag2, lwfrag2, b2, hA);
    k_mlp    <<<NPAIRS / 16, 512, 0, stream>>>(hA, drugs, targets, fc1frag, fc1b, fc2W, fc2b, outp);
}